// Round 1
// baseline (2672.687 us; speedup 1.0000x reference)
//
#include <hip/hip_runtime.h>
#include <cstdint>

// ---------------- problem constants ----------------
#define NB   16
#define LQN  300
#define DM   256
#define NH   8
#define DH   32
#define NLV  3
#define NP   4
#define DFFN 1024
#define NLAY 6
#define TT   7168
#define MROW (NB*LQN)   // 4800
#define SROW (NB*TT)    // 114688

typedef __attribute__((ext_vector_type(8))) short bf16x8;
typedef __attribute__((ext_vector_type(4))) float f32x4;

__device__ __forceinline__ float bf2f(short u) {
  unsigned x = ((unsigned)(unsigned short)u) << 16;
  return __builtin_bit_cast(float, x);
}
__device__ __forceinline__ short f2bf(float f) {
  unsigned u = __builtin_bit_cast(unsigned, f);
  u += 0x7fffu + ((u >> 16) & 1u);   // RNE
  return (short)(u >> 16);
}
__device__ __forceinline__ void load_lds16(const void* g, void* l) {
  __builtin_amdgcn_global_load_lds(
      (const __attribute__((address_space(1))) unsigned int*)g,
      (__attribute__((address_space(3))) unsigned int*)l, 16, 0, 0);
}

// ---------------- weight/src fp32->bf16 conversion (one launch) ----------------
struct CvtPtrs { const float* p[13]; };

__global__ __launch_bounds__(256)
void cvt_all_kernel(CvtPtrs ptrs, short* __restrict__ dst)
{
  const long gid = (long)blockIdx.x*256 + threadIdx.x;  // float4 units
  const long cums[14] = {0,32768,49152,65536,81920,376832,475136,512000,
                         548864,647168,745472,1138688,1531904,8871936};
  int s = 0;
  #pragma unroll
  for (int i = 1; i < 13; ++i) s += (gid >= cums[i]) ? 1 : 0;
  const float4 v = ((const float4*)ptrs.p[s])[gid - cums[s]];
  ((short4*)dst)[gid] = make_short4(f2bf(v.x), f2bf(v.y), f2bf(v.z), f2bf(v.w));
}

// ---------------- GEMM: C[M,N] = A[M,K] @ B[N,K]^T + bias ----------------
// EPI: 0=none, 1=relu, 2=qpos (Cf=qpos=v*rawq ; Cb=bf16(resid+qpos))
template<int EPI>
__global__ __launch_bounds__(256)
void gemm_bt(const short* __restrict__ A, const short* __restrict__ B,
             const float* __restrict__ bias,
             float* __restrict__ Cf, short* __restrict__ Cb,
             int M, int N, int K, int ldc, int coff,
             const unsigned char* __restrict__ rowmask,
             const float* __restrict__ rawq, const float* __restrict__ resid)
{
  __shared__ short As[128*64];
  __shared__ short Bs[128*64];
  const int tid  = threadIdx.x;
  const int wid  = tid >> 6;
  const int lane = tid & 63;
  const int wr = wid >> 1, wc = wid & 1;
  const int fr = lane & 15, fq = lane >> 4;
  const int bm = blockIdx.x, bn = blockIdx.y;

  const int srow = wid*8 + (lane >> 3);
  const int scol = (lane & 7) * 8;          // shorts (16B)

  int arow[4], brow[4];
  #pragma unroll
  for (int i = 0; i < 4; ++i) {
    int r  = bm*128 + i*32 + srow; arow[i] = r  < M ? r  : M-1;
    int rb = bn*128 + i*32 + srow; brow[i] = rb < N ? rb : N-1;
  }

  f32x4 acc[4][4] = {};

  for (int k0 = 0; k0 < K; k0 += 64) {
    #pragma unroll
    for (int i = 0; i < 4; ++i) {
      load_lds16(A + (long)arow[i]*K + k0 + scol, &As[(i*32 + wid*8)*64]);
      load_lds16(B + (long)brow[i]*K + k0 + scol, &Bs[(i*32 + wid*8)*64]);
    }
    __syncthreads();
    #pragma unroll
    for (int kk = 0; kk < 64; kk += 32) {
      bf16x8 af[4], bfr[4];
      #pragma unroll
      for (int mi = 0; mi < 4; ++mi)
        af[mi] = *(const bf16x8*)&As[(wr*64 + mi*16 + fr)*64 + kk + fq*8];
      #pragma unroll
      for (int ni = 0; ni < 4; ++ni)
        bfr[ni] = *(const bf16x8*)&Bs[(wc*64 + ni*16 + fr)*64 + kk + fq*8];
      #pragma unroll
      for (int mi = 0; mi < 4; ++mi)
        #pragma unroll
        for (int ni = 0; ni < 4; ++ni)
          acc[mi][ni] = __builtin_amdgcn_mfma_f32_16x16x32_bf16(af[mi], bfr[ni], acc[mi][ni], 0, 0, 0);
    }
    __syncthreads();
  }

  #pragma unroll
  for (int mi = 0; mi < 4; ++mi) {
    #pragma unroll
    for (int r = 0; r < 4; ++r) {
      const int grow = bm*128 + wr*64 + mi*16 + fq*4 + r;
      if (grow >= M) continue;
      float msc = 1.0f;
      if (rowmask) msc = rowmask[grow] ? 0.0f : 1.0f;
      #pragma unroll
      for (int ni = 0; ni < 4; ++ni) {
        const int gcol = bn*128 + wc*64 + ni*16 + fr;
        if (gcol >= N) continue;
        float v = acc[mi][ni][r] + bias[gcol];
        if (EPI == 1) v = fmaxf(v, 0.0f);
        v *= msc;
        const long off = (long)grow*ldc + coff + gcol;
        if (EPI == 2) {
          const float qp = v * rawq[off];
          Cf[off] = qp;
          Cb[off] = f2bf(resid[off] + qp);
        } else {
          if (Cf) Cf[off] = v;
          if (Cb) Cb[off] = f2bf(v);
        }
      }
    }
  }
}

// ---------------- out = tgt (f32 + bf16 copies) ----------------
__global__ __launch_bounds__(256)
void ew0_kernel(const float* __restrict__ tgt, float* __restrict__ out, short* __restrict__ outbf)
{
  const long i = (long)blockIdx.x*256 + threadIdx.x;
  const float4 v = ((const float4*)tgt)[i];
  ((float4*)out)[i] = v;
  ((short4*)outbf)[i] = make_short4(f2bf(v.x), f2bf(v.y), f2bf(v.z), f2bf(v.w));
}

// ---------------- ref / ref_in / sine embedding ----------------
__global__ __launch_bounds__(256)
void init_ref_kernel(const float* __restrict__ seg, const float* __restrict__ dur,
                     const float* __restrict__ valid,
                     short* __restrict__ sinebf, float* __restrict__ refin)
{
  const int m = blockIdx.x;          // n*300+q
  const int n = m / LQN;
  const int t = threadIdx.x;
  const float c = seg[(long)m*2 + 0];
  const float w = __expf(seg[(long)m*2 + 1]);
  const float e = (float)(t & ~1) * (1.0f/256.0f);     // 2*(i//2)/D
  const float invdim = __expf(-e * 9.2103403719761836f); // 10000^-e
  const float twopi = 6.2831853071795864f;
  const float a0 = c * twopi * invdim;
  const float a1 = w * twopi * invdim;
  const float v0 = (t & 1) ? cosf(a0) : sinf(a0);
  const float v1 = (t & 1) ? cosf(a1) : sinf(a1);
  sinebf[(long)m*512 + t]       = f2bf(v0);
  sinebf[(long)m*512 + 256 + t] = f2bf(v1);
  if (t < 6) {
    const int l = t >> 1, cc = t & 1;
    const float rv = cc ? w : c;
    refin[(long)m*6 + l*2 + cc] = rv / dur[n] * valid[n*NLV + l];
  }
}

// ---------------- MHA (per (n,h,row-half) block; online softmax) ----------------
__global__ __launch_bounds__(192)
void attn_kernel(const float* __restrict__ qk, const float* __restrict__ vv,
                 short* __restrict__ outb)
{
  __shared__ float kl[LQN*DH];
  __shared__ float vl[LQN*DH];
  const int b = blockIdx.x;
  const int half = b & 1;
  const int h = (b >> 1) & 7;
  const int n = b >> 4;
  const int tid = threadIdx.x;
  for (int t = tid; t < LQN*DH; t += 192) {
    const int j = t >> 5, d = t & 31;
    kl[t] = qk[((long)(n*LQN + j))*512 + 256 + h*DH + d];
    vl[t] = vv[((long)(n*LQN + j))*DM  + h*DH + d];
  }
  __syncthreads();
  if (tid < 150) {
    const int q = half*150 + tid;
    float qr[DH];
    #pragma unroll
    for (int d = 0; d < DH; ++d)
      qr[d] = qk[((long)(n*LQN + q))*512 + h*DH + d] * 0.17677669529663687f;
    float mx = -1e30f, l = 0.0f;
    float acc[DH] = {};
    for (int j = 0; j < LQN; ++j) {
      float s = 0.0f;
      #pragma unroll
      for (int d = 0; d < DH; ++d) s = fmaf(qr[d], kl[j*DH+d], s);
      if (s > mx) {
        const float cr = __expf(mx - s);
        l *= cr;
        #pragma unroll
        for (int d = 0; d < DH; ++d) acc[d] *= cr;
        mx = s;
      }
      const float p = __expf(s - mx);
      l += p;
      #pragma unroll
      for (int d = 0; d < DH; ++d) acc[d] = fmaf(p, vl[j*DH+d], acc[d]);
    }
    const float inv = 1.0f / l;
    #pragma unroll
    for (int d = 0; d < DH; ++d)
      outb[((long)(n*LQN + q))*DM + h*DH + d] = f2bf(acc[d]*inv);
  }
}

// ---------------- residual + LayerNorm (+ optional caq = y+qpos) ----------------
__global__ __launch_bounds__(256)
void ln_kernel(const float* __restrict__ resid, const float* __restrict__ delta,
               const float* __restrict__ g, const float* __restrict__ b,
               float* __restrict__ of, short* __restrict__ ob,
               const float* __restrict__ qpos, short* __restrict__ caqb)
{
  const int m = blockIdx.x, c = threadIdx.x;
  const long idx = (long)m*DM + c;
  const float x = resid[idx] + delta[idx];
  float s = x, s2 = x*x;
  #pragma unroll
  for (int o = 1; o < 64; o <<= 1) { s += __shfl_xor(s, o); s2 += __shfl_xor(s2, o); }
  __shared__ float rs[4], rs2[4];
  const int w = c >> 6;
  if ((c & 63) == 0) { rs[w] = s; rs2[w] = s2; }
  __syncthreads();
  s  = rs[0]+rs[1]+rs[2]+rs[3];
  s2 = rs2[0]+rs2[1]+rs2[2]+rs2[3];
  const float mean = s * (1.0f/DM);
  const float var  = s2 * (1.0f/DM) - mean*mean;
  const float y = (x - mean) * rsqrtf(var + 1e-5f) * g[c] + b[c];
  of[idx] = y;
  if (ob) ob[idx] = f2bf(y);
  if (qpos) caqb[idx] = f2bf(y + qpos[idx]);
}

// ---------------- deform sampling prep: aw softmax + bilinear idx/weights ----------------
__global__ __launch_bounds__(256)
void prep_kernel(const float* __restrict__ offaw, const float* __restrict__ refin,
                 const int* __restrict__ tlens, const int* __restrict__ lstart,
                 int2* __restrict__ sI, float2* __restrict__ sW)
{
  const int idx = blockIdx.x*256 + threadIdx.x;    // (n*300+q)*8 + h
  if (idx >= MROW*NH) return;
  const int h = idx & 7;
  const int m = idx >> 3;
  const float* row = offaw + (long)m*192;
  float aw[12];
  float mx = -1e30f;
  #pragma unroll
  for (int lp = 0; lp < 12; ++lp) { aw[lp] = row[96 + h*12 + lp]; mx = fmaxf(mx, aw[lp]); }
  float sum = 0.0f;
  #pragma unroll
  for (int lp = 0; lp < 12; ++lp) { aw[lp] = __expf(aw[lp]-mx); sum += aw[lp]; }
  const float invs = 1.0f / sum;
  #pragma unroll
  for (int lp = 0; lp < 12; ++lp) {
    const int l = lp >> 2;
    const int tli = tlens[l];
    const float off = row[h*12 + lp];
    const float loc = refin[(long)m*6 + l*2] + off * 0.25f * refin[(long)m*6 + l*2 + 1] * 0.5f;
    const float x = loc * (float)tli - 0.5f;
    const float x0f = floorf(x);
    const float f = x - x0f;
    const int x0 = (int)x0f;
    const int i0 = lstart[l] + min(max(x0,   0), tli-1);
    const int i1 = lstart[l] + min(max(x0+1, 0), tli-1);
    const float wgt = aw[lp]*invs;
    const float w0 = (x0   >= 0 && x0   < tli) ? wgt*(1.0f-f) : 0.0f;
    const float w1 = (x0+1 >= 0 && x0+1 < tli) ? wgt*f        : 0.0f;
    sI[(long)idx*12 + lp] = make_int2(i0, i1);
    sW[(long)idx*12 + lp] = make_float2(w0, w1);
  }
}

// ---------------- sampling gather-MAC ----------------
__global__ __launch_bounds__(256)
void sample_kernel(const short* __restrict__ val, const int2* __restrict__ sI,
                   const float2* __restrict__ sW, short* __restrict__ cab)
{
  const int m = blockIdx.x;       // n*300+q
  const int n = m / LQN;
  const int tid = threadIdx.x;    // channel = h*32+d
  __shared__ int2  lI[96];
  __shared__ float2 lW[96];
  if (tid < 96) { lI[tid] = sI[(long)m*96 + tid]; lW[tid] = sW[(long)m*96 + tid]; }
  __syncthreads();
  const int h = tid >> 5;
  const short* vb = val + (long)n*TT*DM;
  float acc = 0.0f;
  #pragma unroll
  for (int lp = 0; lp < 12; ++lp) {
    const int e = h*12 + lp;
    const int2 ii = lI[e];
    const float2 ww = lW[e];
    acc += ww.x * bf2f(vb[(long)ii.x*DM + tid]) + ww.y * bf2f(vb[(long)ii.y*DM + tid]);
  }
  cab[(long)m*DM + tid] = f2bf(acc);
}

// ---------------- host side ----------------
static inline void gemm(hipStream_t st, int epi, const short* A, const short* B,
                        const float* bias, float* Cf, short* Cb,
                        int M, int N, int K, int ldc, int coff = 0,
                        const unsigned char* rmask = nullptr,
                        const float* rawq = nullptr, const float* resid = nullptr)
{
  dim3 g((M+127)/128, (N+127)/128), blk(256);
  if (epi == 0)      gemm_bt<0><<<g, blk, 0, st>>>(A,B,bias,Cf,Cb,M,N,K,ldc,coff,rmask,rawq,resid);
  else if (epi == 1) gemm_bt<1><<<g, blk, 0, st>>>(A,B,bias,Cf,Cb,M,N,K,ldc,coff,rmask,rawq,resid);
  else               gemm_bt<2><<<g, blk, 0, st>>>(A,B,bias,Cf,Cb,M,N,K,ldc,coff,rmask,rawq,resid);
}

extern "C" void kernel_launch(void* const* d_in, const int* in_sizes, int n_in,
                              void* d_out, int out_size, void* d_ws, size_t ws_size,
                              hipStream_t stream)
{
  const float* tgt    = (const float*)d_in[0];
  const float* seg    = (const float*)d_in[1];
  const float* dur    = (const float*)d_in[2];
  const float* src    = (const float*)d_in[3];
  const int*   tlens  = (const int*)d_in[4];
  const int*   lstart = (const int*)d_in[5];
  const float* valid  = (const float*)d_in[6];
  const unsigned char* pmask = (const unsigned char*)d_in[7];
  const float* grid_w0 = (const float*)d_in[8];
  const float* grid_b0 = (const float*)d_in[9];
  const float* grid_w1 = (const float*)d_in[10];
  const float* grid_b1 = (const float*)d_in[11];
  const float* qs_w0 = (const float*)d_in[12];
  const float* qs_b0 = (const float*)d_in[13];
  const float* qs_w1 = (const float*)d_in[14];
  const float* qs_b1 = (const float*)d_in[15];
  const float* sa_in_w  = (const float*)d_in[16];
  const float* sa_in_b  = (const float*)d_in[17];
  const float* sa_out_w = (const float*)d_in[18];
  const float* sa_out_b = (const float*)d_in[19];
  const float* n1_g = (const float*)d_in[20];
  const float* n1_b = (const float*)d_in[21];
  const float* n2_g = (const float*)d_in[22];
  const float* n2_b = (const float*)d_in[23];
  const float* n3_g = (const float*)d_in[24];
  const float* n3_b = (const float*)d_in[25];
  const float* off_w = (const float*)d_in[26];
  const float* off_b = (const float*)d_in[27];
  const float* aw_w  = (const float*)d_in[28];
  const float* aw_b  = (const float*)d_in[29];
  const float* val_w = (const float*)d_in[30];
  const float* val_b = (const float*)d_in[31];
  const float* outp_w = (const float*)d_in[32];
  const float* outp_b = (const float*)d_in[33];
  const float* ffn_w1 = (const float*)d_in[34];
  const float* ffn_b1 = (const float*)d_in[35];
  const float* ffn_w2 = (const float*)d_in[36];
  const float* ffn_b2 = (const float*)d_in[37];

  // ---- bf16 weight region offsets (shorts, within wbf) ----
  const long W_G0=0, W_G1=131072, W_QS0=196608, W_QS1=262144, W_SAIN=327680,
             W_SAOUT=1507328, W_OFF=1900544, W_AW=2048000, W_VAL=2195456,
             W_OUTP=2588672, W_FFN1=2981888, W_FFN2=4554752, W_SRC=6127616;

  char* ws = (char*)d_ws;
  short* wbf    = (short*)(ws + 0);                 // 70,975,488 B (weights+src bf16)
  short* srcbf  = wbf + W_SRC;
  short* valbf  = (short*)(ws + 70975488);          // 58,720,256
  short* sinebf = (short*)(ws + 129695744);         // 4,915,200
  short* ghbf   = (short*)(ws + 134610944);         // 2,457,600
  float* rawq   = (float*)(ws + 137068544);         // 4,915,200
  float* out    = (float*)(ws + 141983744);         // 4,915,200
  short* outbf  = (short*)(ws + 146898944);         // 2,457,600
  short* t1bf   = (short*)(ws + 149356544);         // 2,457,600
  float* qpos   = (float*)(ws + 151814144);         // 4,915,200
  short* qbf    = (short*)(ws + 156729344);         // 2,457,600
  float* qkf    = (float*)(ws + 159186944);         // 9,830,400
  float* vf     = (float*)(ws + 169017344);         // 4,915,200
  short* attnbf = (short*)(ws + 173932544);         // 2,457,600
  float* tmpf   = (float*)(ws + 176390144);         // 4,915,200
  short* caqb   = (short*)(ws + 181305344);         // 2,457,600
  float* offaw  = (float*)(ws + 183762944);         // 3,686,400
  int2*  sIdx   = (int2*) (ws + 187449344);         // 3,686,400
  float2* sWgt  = (float2*)(ws + 191135744);        // 3,686,400
  short* cabf   = (short*)(ws + 194822144);         // 2,457,600
  short* ffnhbf = (short*)(ws + 197279744);         // 9,830,400
  float* refin  = (float*)(ws + 207110144);         // 115,200

  // ---- one-time precompute ----
  CvtPtrs cp;
  cp.p[0]=grid_w0; cp.p[1]=grid_w1; cp.p[2]=qs_w0; cp.p[3]=qs_w1; cp.p[4]=sa_in_w;
  cp.p[5]=sa_out_w; cp.p[6]=off_w; cp.p[7]=aw_w; cp.p[8]=val_w; cp.p[9]=outp_w;
  cp.p[10]=ffn_w1; cp.p[11]=ffn_w2; cp.p[12]=src;
  cvt_all_kernel<<<dim3(34656), dim3(256), 0, stream>>>(cp, wbf);

  ew0_kernel<<<dim3(1200), dim3(256), 0, stream>>>(tgt, out, outbf);
  init_ref_kernel<<<dim3(MROW), dim3(256), 0, stream>>>(seg, dur, valid, sinebf, refin);

  // raw_qpos = MLP2(sine; grid)
  gemm(stream, 1, sinebf, wbf + W_G0, grid_b0, nullptr, ghbf, MROW, 256, 512, 256);
  gemm(stream, 0, ghbf,   wbf + W_G1, grid_b1, rawq, nullptr, MROW, 256, 256, 256);

  for (int l = 0; l < NLAY; ++l) {
    // qpos = MLP2(out; qs) * rawq ; qbf = bf16(out + qpos)
    gemm(stream, 1, outbf, wbf + W_QS0, qs_b0, nullptr, t1bf, MROW, 256, 256, 256);
    gemm(stream, 2, t1bf,  wbf + W_QS1, qs_b1, qpos, qbf, MROW, 256, 256, 256, 0,
         nullptr, rawq, out);
    // self-attention projections
    gemm(stream, 0, qbf, wbf + W_SAIN + (long)l*196608, sa_in_b + l*768,
         qkf, nullptr, MROW, 512, 256, 512);
    gemm(stream, 0, outbf, wbf + W_SAIN + (long)l*196608 + 512*256, sa_in_b + l*768 + 512,
         vf, nullptr, MROW, 256, 256, 256);
    attn_kernel<<<dim3(NB*NH*2), dim3(192), 0, stream>>>(qkf, vf, attnbf);
    gemm(stream, 0, attnbf, wbf + W_SAOUT + (long)l*65536, sa_out_b + l*256,
         tmpf, nullptr, MROW, 256, 256, 256);
    ln_kernel<<<dim3(MROW), dim3(256), 0, stream>>>(out, tmpf, n1_g + l*256, n1_b + l*256,
                                                    out, outbf, qpos, caqb);
    // deformable attention
    gemm(stream, 0, caqb, wbf + W_OFF + (long)l*24576, off_b + l*96,
         offaw, nullptr, MROW, 96, 256, 192, 0);
    gemm(stream, 0, caqb, wbf + W_AW + (long)l*24576, aw_b + l*96,
         offaw, nullptr, MROW, 96, 256, 192, 96);
    prep_kernel<<<dim3(150), dim3(256), 0, stream>>>(offaw, refin, tlens, lstart, sIdx, sWgt);
    gemm(stream, 0, srcbf, wbf + W_VAL + (long)l*65536, val_b + l*256,
         nullptr, valbf, SROW, 256, 256, 256, 0, pmask);
    sample_kernel<<<dim3(MROW), dim3(256), 0, stream>>>(valbf, sIdx, sWgt, cabf);
    gemm(stream, 0, cabf, wbf + W_OUTP + (long)l*65536, outp_b + l*256,
         tmpf, nullptr, MROW, 256, 256, 256);
    ln_kernel<<<dim3(MROW), dim3(256), 0, stream>>>(out, tmpf, n2_g + l*256, n2_b + l*256,
                                                    out, outbf, nullptr, nullptr);
    // FFN
    gemm(stream, 1, outbf, wbf + W_FFN1 + (long)l*262144, ffn_b1 + l*1024,
         nullptr, ffnhbf, MROW, 1024, 256, 1024);
    gemm(stream, 0, ffnhbf, wbf + W_FFN2 + (long)l*262144, ffn_b2 + l*256,
         tmpf, nullptr, MROW, 256, 1024, 256);
    float* of = (l == NLAY-1) ? (float*)d_out : out;
    ln_kernel<<<dim3(MROW), dim3(256), 0, stream>>>(out, tmpf, n3_g + l*256, n3_b + l*256,
                                                    of, outbf, nullptr, nullptr);
  }
}

// Round 2
// 1358.192 us; speedup vs baseline: 1.9678x; 1.9678x over previous
//
#include <hip/hip_runtime.h>
#include <cstdint>

#define NB   16
#define LQN  300
#define DM   256
#define NH   8
#define DH   32
#define NLV  3
#define DFFN 1024
#define NLAY 6
#define TT   7168
#define MROW (NB*LQN)   // 4800
#define SROW (NB*TT)    // 114688

typedef __attribute__((ext_vector_type(8))) short bf16x8;
typedef __attribute__((ext_vector_type(4))) float f32x4;

__device__ __forceinline__ float bf2f(short u) {
  unsigned x = ((unsigned)(unsigned short)u) << 16;
  return __builtin_bit_cast(float, x);
}
__device__ __forceinline__ short f2bf(float f) {
  unsigned u = __builtin_bit_cast(unsigned, f);
  u += 0x7fffu + ((u >> 16) & 1u);   // RNE
  return (short)(u >> 16);
}
__device__ __forceinline__ void load_lds16(const void* g, void* l) {
  __builtin_amdgcn_global_load_lds(
      (const __attribute__((address_space(1))) unsigned int*)g,
      (__attribute__((address_space(3))) unsigned int*)l, 16, 0, 0);
}
#define MFMA(a,b,c) __builtin_amdgcn_mfma_f32_16x16x32_bf16((a),(b),(c),0,0,0)

// ---------------- weight/src fp32->bf16 conversion ----------------
struct CvtPtrs { const float* p[13]; };

__global__ __launch_bounds__(256)
void cvt_all_kernel(CvtPtrs ptrs, short* __restrict__ dst)
{
  const long gid = (long)blockIdx.x*256 + threadIdx.x;  // float4 units
  const long cums[14] = {0,32768,49152,65536,81920,376832,475136,512000,
                         548864,647168,745472,1138688,1531904,8871936};
  int s = 0;
  #pragma unroll
  for (int i = 1; i < 13; ++i) s += (gid >= cums[i]) ? 1 : 0;
  const long rel = gid - cums[s];
  const float4 v = ((const float4*)ptrs.p[s])[rel];
  long dstIdx = gid;
  if (s == 6) { const long l = rel/6144, w = rel%6144; dstIdx = 475136 + l*12288 + w; }
  else if (s == 7) { const long l = rel/6144, w = rel%6144; dstIdx = 475136 + l*12288 + 6144 + w; }
  ((short4*)dst)[dstIdx] = make_short4(f2bf(v.x), f2bf(v.y), f2bf(v.z), f2bf(v.w));
}

// ---------------- GEMM 128x128 (val projection): Cb = bf16(A@B^T + bias), rowmask ----------------
__global__ __launch_bounds__(256)
void gemm128(const short* __restrict__ A, const short* __restrict__ B,
             const float* __restrict__ bias, short* __restrict__ Cb,
             int M, int N, int K, int ldc,
             const unsigned char* __restrict__ rowmask)
{
  __shared__ short As[128*64];
  __shared__ short Bs[128*64];
  const int tid  = threadIdx.x;
  const int wid  = tid >> 6;
  const int lane = tid & 63;
  const int wr = wid >> 1, wc = wid & 1;
  const int fr = lane & 15, fq = lane >> 4;
  const int bm = blockIdx.x, bn = blockIdx.y;
  const int srow = wid*8 + (lane >> 3);
  const int scol = (lane & 7) * 8;

  int arow[4], brow[4];
  #pragma unroll
  for (int i = 0; i < 4; ++i) {
    int r  = bm*128 + i*32 + srow; arow[i] = r  < M ? r  : M-1;
    int rb = bn*128 + i*32 + srow; brow[i] = rb < N ? rb : N-1;
  }
  f32x4 acc[4][4] = {};
  for (int k0 = 0; k0 < K; k0 += 64) {
    #pragma unroll
    for (int i = 0; i < 4; ++i) {
      load_lds16(A + (long)arow[i]*K + k0 + scol, &As[(i*32 + wid*8)*64]);
      load_lds16(B + (long)brow[i]*K + k0 + scol, &Bs[(i*32 + wid*8)*64]);
    }
    __syncthreads();
    #pragma unroll
    for (int kk = 0; kk < 64; kk += 32) {
      bf16x8 af[4], bfr[4];
      #pragma unroll
      for (int mi = 0; mi < 4; ++mi)
        af[mi] = *(const bf16x8*)&As[(wr*64 + mi*16 + fr)*64 + kk + fq*8];
      #pragma unroll
      for (int ni = 0; ni < 4; ++ni)
        bfr[ni] = *(const bf16x8*)&Bs[(wc*64 + ni*16 + fr)*64 + kk + fq*8];
      #pragma unroll
      for (int mi = 0; mi < 4; ++mi)
        #pragma unroll
        for (int ni = 0; ni < 4; ++ni)
          acc[mi][ni] = MFMA(af[mi], bfr[ni], acc[mi][ni]);
    }
    __syncthreads();
  }
  #pragma unroll
  for (int mi = 0; mi < 4; ++mi) {
    #pragma unroll
    for (int r = 0; r < 4; ++r) {
      const int grow = bm*128 + wr*64 + mi*16 + fq*4 + r;
      if (grow >= M) continue;
      const float msc = rowmask ? (rowmask[grow] ? 0.0f : 1.0f) : 1.0f;
      #pragma unroll
      for (int ni = 0; ni < 4; ++ni) {
        const int gcol = bn*128 + wc*64 + ni*16 + fr;
        if (gcol >= N) continue;
        const float v = (acc[mi][ni][r] + bias[gcol]) * msc;
        Cb[(long)grow*ldc + gcol] = f2bf(v);
      }
    }
  }
}

// ---------------- GEMM 64x64 tile, A[M,K] @ B[N,K]^T + bias ----------------
// EPI: 0 plain (Cf/Cb optional), 1 relu->Cb, 2 qpos, 3 sain-route, 4 two-bias->Cf
template<int EPI>
__global__ __launch_bounds__(256)
void gemm64(const short* __restrict__ A, const short* __restrict__ B,
            const float* __restrict__ bias, const float* __restrict__ bias2,
            float* __restrict__ Cf, short* __restrict__ Cb, short* __restrict__ Cb2,
            int M, int N, int K, int ldc,
            const float* __restrict__ rawq, const float* __restrict__ resid)
{
  __shared__ short As[64*64];
  __shared__ short Bs[64*64];
  const int tid = threadIdx.x, wid = tid >> 6, lane = tid & 63;
  const int wr = wid >> 1, wc = wid & 1;
  const int fr = lane & 15, fq = lane >> 4;
  const int bm = blockIdx.x, bn = blockIdx.y;
  const int sr = lane >> 3, sc8 = (lane & 7)*8;

  f32x4 acc[2][2] = {};
  for (int k0 = 0; k0 < K; k0 += 64) {
    #pragma unroll
    for (int i = 0; i < 2; ++i) {
      const int rr = wid*16 + i*8 + sr;
      load_lds16(A + (long)(bm*64 + rr)*K + k0 + sc8, &As[(wid*16 + i*8)*64]);
      load_lds16(B + (long)(bn*64 + rr)*K + k0 + sc8, &Bs[(wid*16 + i*8)*64]);
    }
    __syncthreads();
    #pragma unroll
    for (int kk = 0; kk < 64; kk += 32) {
      bf16x8 af[2], bv[2];
      #pragma unroll
      for (int mi = 0; mi < 2; ++mi)
        af[mi] = *(const bf16x8*)&As[(wr*32 + mi*16 + fr)*64 + kk + fq*8];
      #pragma unroll
      for (int ni = 0; ni < 2; ++ni)
        bv[ni] = *(const bf16x8*)&Bs[(wc*32 + ni*16 + fr)*64 + kk + fq*8];
      #pragma unroll
      for (int mi = 0; mi < 2; ++mi)
        #pragma unroll
        for (int ni = 0; ni < 2; ++ni)
          acc[mi][ni] = MFMA(af[mi], bv[ni], acc[mi][ni]);
    }
    __syncthreads();
  }
  #pragma unroll
  for (int mi = 0; mi < 2; ++mi) {
    #pragma unroll
    for (int r = 0; r < 4; ++r) {
      const int grow = bm*64 + wr*32 + mi*16 + fq*4 + r;
      #pragma unroll
      for (int ni = 0; ni < 2; ++ni) {
        const int gcol = bn*64 + wc*32 + ni*16 + fr;
        float v = acc[mi][ni][r];
        if (EPI == 4) v += (gcol < 96) ? bias[gcol] : bias2[gcol-96];
        else v += bias[gcol];
        const long off = (long)grow*ldc + gcol;
        if (EPI == 0) {
          if (Cf) Cf[off] = v;
          if (Cb) Cb[off] = f2bf(v);
        } else if (EPI == 1) {
          Cb[off] = f2bf(fmaxf(v, 0.0f));
        } else if (EPI == 2) {
          const float qp = v * rawq[off];
          Cf[off] = qp;
          Cb[off] = f2bf(resid[off] + qp);
        } else if (EPI == 3) {
          if (grow < MROW) { if (gcol < 512) Cb[(long)grow*512 + gcol] = f2bf(v); }
          else             { if (gcol >= 512) Cb2[(long)(grow-MROW)*256 + gcol-512] = f2bf(v); }
        } else if (EPI == 4) {
          Cf[off] = v;
        }
      }
    }
  }
}

// ---------------- out = tgt (f32 + bf16 copies) ----------------
__global__ __launch_bounds__(256)
void ew0_kernel(const float* __restrict__ tgt, float* __restrict__ out, short* __restrict__ outbf)
{
  const long i = (long)blockIdx.x*256 + threadIdx.x;
  const float4 v = ((const float4*)tgt)[i];
  ((float4*)out)[i] = v;
  ((short4*)outbf)[i] = make_short4(f2bf(v.x), f2bf(v.y), f2bf(v.z), f2bf(v.w));
}

// ---------------- ref / ref_in / sine embedding ----------------
__global__ __launch_bounds__(256)
void init_ref_kernel(const float* __restrict__ seg, const float* __restrict__ dur,
                     const float* __restrict__ valid,
                     short* __restrict__ sinebf, float* __restrict__ refin)
{
  const int m = blockIdx.x;
  const int n = m / LQN;
  const int t = threadIdx.x;
  const float c = seg[(long)m*2 + 0];
  const float w = __expf(seg[(long)m*2 + 1]);
  const float e = (float)(t & ~1) * (1.0f/256.0f);
  const float invdim = __expf(-e * 9.2103403719761836f);
  const float twopi = 6.2831853071795864f;
  const float a0 = c * twopi * invdim;
  const float a1 = w * twopi * invdim;
  const float v0 = (t & 1) ? cosf(a0) : sinf(a0);
  const float v1 = (t & 1) ? cosf(a1) : sinf(a1);
  sinebf[(long)m*512 + t]       = f2bf(v0);
  sinebf[(long)m*512 + 256 + t] = f2bf(v1);
  if (t < 6) {
    const int l = t >> 1, cc = t & 1;
    const float rv = cc ? w : c;
    refin[(long)m*6 + l*2 + cc] = rv / dur[n] * valid[n*NLV + l];
  }
}

// ---------------- MFMA attention: grid (n,h,half)=256 blocks, 4 waves ----------------
#define KPAD 320
#define KSTR 40    // K LDS row stride (shorts)
#define VSTR 328   // Vt LDS row stride
#define PSTR 328   // P LDS row stride

__global__ __launch_bounds__(256)
void attn_mfma(const short* __restrict__ qk, const short* __restrict__ vv,
               short* __restrict__ outb)
{
  __shared__ short Kl[KPAD*KSTR];     // [k][d]
  __shared__ short Vt[DH*VSTR];       // [d][k]
  __shared__ short Pl[4][16*PSTR];    // per-wave P [q][k]
  const int b = blockIdx.x;
  const int half = b & 1, h = (b >> 1) & 7, n = b >> 4;
  const int tid = threadIdx.x, wid = tid >> 6, lane = tid & 63;
  const int fr = lane & 15, fq = lane >> 4;

  const short* qkn = qk + (long)n*LQN*512;
  const short* vn  = vv + (long)n*LQN*256;

  for (int t = tid; t < KPAD*4; t += 256) {
    const int r = t >> 2, c = t & 3;
    bf16x8 kv = {}, vw = {};
    if (r < LQN) {
      kv = *(const bf16x8*)(qkn + (long)r*512 + 256 + h*32 + c*8);
      vw = *(const bf16x8*)(vn  + (long)r*256 + h*32 + c*8);
    }
    *(bf16x8*)&Kl[r*KSTR + c*8] = kv;
    #pragma unroll
    for (int j = 0; j < 8; ++j) Vt[(c*8+j)*VSTR + r] = vw[j];
  }
  for (int t = tid; t < 4*16*24; t += 256) {
    const int w = t / (16*24), rr = (t / 24) & 15, cc = t % 24;
    Pl[w][rr*PSTR + 304 + cc] = 0;
  }
  __syncthreads();

  const int tlo = half ? 10 : 0, thi = half ? 19 : 10;
  const float scl2 = 0.17677669529663687f * 1.4426950408889634f;

  for (int qt = tlo + wid; qt < thi; qt += 4) {
    const int q0 = qt * 16;
    const int qrow = min(q0 + fr, LQN-1);
    const bf16x8 qf = *(const bf16x8*)(qkn + (long)qrow*512 + h*32 + fq*8);
    f32x4 s[19];
    #pragma unroll
    for (int t = 0; t < 19; ++t) {
      const bf16x8 kf = *(const bf16x8*)&Kl[(t*16+fr)*KSTR + fq*8];
      s[t] = MFMA(qf, kf, ((f32x4){0.f,0.f,0.f,0.f}));
    }
    float mx[4] = {-3e38f,-3e38f,-3e38f,-3e38f};
    #pragma unroll
    for (int t = 0; t < 19; ++t) {
      const bool valid = (t < 18) || (fr < 12);
      #pragma unroll
      for (int r = 0; r < 4; ++r) if (valid) mx[r] = fmaxf(mx[r], s[t][r]);
    }
    #pragma unroll
    for (int r = 0; r < 4; ++r) {
      #pragma unroll
      for (int o = 1; o < 16; o <<= 1) mx[r] = fmaxf(mx[r], __shfl_xor(mx[r], o));
      mx[r] *= scl2;
    }
    float l[4] = {0.f,0.f,0.f,0.f};
    #pragma unroll
    for (int t = 0; t < 19; ++t) {
      const bool valid = (t < 18) || (fr < 12);
      #pragma unroll
      for (int r = 0; r < 4; ++r) {
        const float p = valid ? exp2f(s[t][r]*scl2 - mx[r]) : 0.0f;
        l[r] += p;
        Pl[wid][(fq*4+r)*PSTR + t*16 + fr] = f2bf(p);
      }
    }
    #pragma unroll
    for (int r = 0; r < 4; ++r) {
      #pragma unroll
      for (int o = 1; o < 16; o <<= 1) l[r] += __shfl_xor(l[r], o);
    }
    f32x4 o0 = {}, o1 = {};
    #pragma unroll
    for (int ck = 0; ck < 10; ++ck) {
      const bf16x8 pf = *(const bf16x8*)&Pl[wid][fr*PSTR + ck*32 + fq*8];
      const bf16x8 v0 = *(const bf16x8*)&Vt[fr*VSTR + ck*32 + fq*8];
      const bf16x8 v1 = *(const bf16x8*)&Vt[(16+fr)*VSTR + ck*32 + fq*8];
      o0 = MFMA(pf, v0, o0);
      o1 = MFMA(pf, v1, o1);
    }
    #pragma unroll
    for (int r = 0; r < 4; ++r) {
      const int qq = q0 + fq*4 + r;
      if (qq < LQN) {
        const float inv = 1.0f / l[r];
        outb[((long)(n*LQN+qq))*256 + h*32 + fr]      = f2bf(o0[r]*inv);
        outb[((long)(n*LQN+qq))*256 + h*32 + 16 + fr] = f2bf(o1[r]*inv);
      }
    }
  }
}

// ---------------- residual + LayerNorm (+ optional caq = y+qpos) ----------------
__global__ __launch_bounds__(256)
void ln_kernel(const float* __restrict__ resid, const float* __restrict__ delta,
               const float* __restrict__ g, const float* __restrict__ b,
               float* __restrict__ of, short* __restrict__ ob,
               const float* __restrict__ qpos, short* __restrict__ caqb)
{
  const int m = blockIdx.x, c = threadIdx.x;
  const long idx = (long)m*DM + c;
  const float x = resid[idx] + delta[idx];
  float s = x, s2 = x*x;
  #pragma unroll
  for (int o = 1; o < 64; o <<= 1) { s += __shfl_xor(s, o); s2 += __shfl_xor(s2, o); }
  __shared__ float rs[4], rs2[4];
  const int w = c >> 6;
  if ((c & 63) == 0) { rs[w] = s; rs2[w] = s2; }
  __syncthreads();
  s  = rs[0]+rs[1]+rs[2]+rs[3];
  s2 = rs2[0]+rs2[1]+rs2[2]+rs2[3];
  const float mean = s * (1.0f/DM);
  const float var  = s2 * (1.0f/DM) - mean*mean;
  const float y = (x - mean) * rsqrtf(var + 1e-5f) * g[c] + b[c];
  of[idx] = y;
  if (ob) ob[idx] = f2bf(y);
  if (qpos) caqb[idx] = f2bf(y + qpos[idx]);
}

// ---------------- deform sampling prep ----------------
__global__ __launch_bounds__(256)
void prep_kernel(const float* __restrict__ offaw, const float* __restrict__ refin,
                 const int* __restrict__ tlens, const int* __restrict__ lstart,
                 int2* __restrict__ sI, float2* __restrict__ sW)
{
  const int idx = blockIdx.x*256 + threadIdx.x;
  if (idx >= MROW*NH) return;
  const int h = idx & 7;
  const int m = idx >> 3;
  const float* row = offaw + (long)m*192;
  float aw[12];
  float mx = -1e30f;
  #pragma unroll
  for (int lp = 0; lp < 12; ++lp) { aw[lp] = row[96 + h*12 + lp]; mx = fmaxf(mx, aw[lp]); }
  float sum = 0.0f;
  #pragma unroll
  for (int lp = 0; lp < 12; ++lp) { aw[lp] = __expf(aw[lp]-mx); sum += aw[lp]; }
  const float invs = 1.0f / sum;
  #pragma unroll
  for (int lp = 0; lp < 12; ++lp) {
    const int l = lp >> 2;
    const int tli = tlens[l];
    const float off = row[h*12 + lp];
    const float loc = refin[(long)m*6 + l*2] + off * 0.25f * refin[(long)m*6 + l*2 + 1] * 0.5f;
    const float x = loc * (float)tli - 0.5f;
    const float x0f = floorf(x);
    const float f = x - x0f;
    const int x0 = (int)x0f;
    const int i0 = lstart[l] + min(max(x0,   0), tli-1);
    const int i1 = lstart[l] + min(max(x0+1, 0), tli-1);
    const float wgt = aw[lp]*invs;
    const float w0 = (x0   >= 0 && x0   < tli) ? wgt*(1.0f-f) : 0.0f;
    const float w1 = (x0+1 >= 0 && x0+1 < tli) ? wgt*f        : 0.0f;
    sI[(long)idx*12 + lp] = make_int2(i0, i1);
    sW[(long)idx*12 + lp] = make_float2(w0, w1);
  }
}

// ---------------- sampling gather-MAC ----------------
__global__ __launch_bounds__(256)
void sample_kernel(const short* __restrict__ val, int ldv,
                   const int2* __restrict__ sI, const float2* __restrict__ sW,
                   short* __restrict__ cab)
{
  const int m = blockIdx.x;
  const int n = m / LQN;
  const int tid = threadIdx.x;
  __shared__ int2  lI[96];
  __shared__ float2 lW[96];
  if (tid < 96) { lI[tid] = sI[(long)m*96 + tid]; lW[tid] = sW[(long)m*96 + tid]; }
  __syncthreads();
  const int h = tid >> 5;
  const short* vb = val + (long)n*TT*ldv;
  float acc = 0.0f;
  #pragma unroll
  for (int lp = 0; lp < 12; ++lp) {
    const int e = h*12 + lp;
    const int2 ii = lI[e];
    const float2 ww = lW[e];
    acc += ww.x * bf2f(vb[(long)ii.x*ldv + tid]) + ww.y * bf2f(vb[(long)ii.y*ldv + tid]);
  }
  cab[(long)m*DM + tid] = f2bf(acc);
}

// ---------------- host side ----------------
static inline void g64(hipStream_t st, int epi, const short* A, const short* B,
                       const float* bias, const float* bias2,
                       float* Cf, short* Cb, short* Cb2,
                       int M, int N, int K, int ldc,
                       const float* rawq = nullptr, const float* resid = nullptr)
{
  dim3 g(M/64, N/64), blk(256);
  switch (epi) {
    case 0: gemm64<0><<<g,blk,0,st>>>(A,B,bias,bias2,Cf,Cb,Cb2,M,N,K,ldc,rawq,resid); break;
    case 1: gemm64<1><<<g,blk,0,st>>>(A,B,bias,bias2,Cf,Cb,Cb2,M,N,K,ldc,rawq,resid); break;
    case 2: gemm64<2><<<g,blk,0,st>>>(A,B,bias,bias2,Cf,Cb,Cb2,M,N,K,ldc,rawq,resid); break;
    case 3: gemm64<3><<<g,blk,0,st>>>(A,B,bias,bias2,Cf,Cb,Cb2,M,N,K,ldc,rawq,resid); break;
    default:gemm64<4><<<g,blk,0,st>>>(A,B,bias,bias2,Cf,Cb,Cb2,M,N,K,ldc,rawq,resid); break;
  }
}

extern "C" void kernel_launch(void* const* d_in, const int* in_sizes, int n_in,
                              void* d_out, int out_size, void* d_ws, size_t ws_size,
                              hipStream_t stream)
{
  const float* tgt    = (const float*)d_in[0];
  const float* seg    = (const float*)d_in[1];
  const float* dur    = (const float*)d_in[2];
  const float* src    = (const float*)d_in[3];
  const int*   tlens  = (const int*)d_in[4];
  const int*   lstart = (const int*)d_in[5];
  const float* valid  = (const float*)d_in[6];
  const unsigned char* pmask = (const unsigned char*)d_in[7];
  const float* grid_w0 = (const float*)d_in[8];
  const float* grid_b0 = (const float*)d_in[9];
  const float* grid_w1 = (const float*)d_in[10];
  const float* grid_b1 = (const float*)d_in[11];
  const float* qs_w0 = (const float*)d_in[12];
  const float* qs_b0 = (const float*)d_in[13];
  const float* qs_w1 = (const float*)d_in[14];
  const float* qs_b1 = (const float*)d_in[15];
  const float* sa_in_w  = (const float*)d_in[16];
  const float* sa_in_b  = (const float*)d_in[17];
  const float* sa_out_w = (const float*)d_in[18];
  const float* sa_out_b = (const float*)d_in[19];
  const float* n1_g = (const float*)d_in[20];
  const float* n1_b = (const float*)d_in[21];
  const float* n2_g = (const float*)d_in[22];
  const float* n2_b = (const float*)d_in[23];
  const float* n3_g = (const float*)d_in[24];
  const float* n3_b = (const float*)d_in[25];
  const float* off_w = (const float*)d_in[26];
  const float* off_b = (const float*)d_in[27];
  const float* aw_w  = (const float*)d_in[28];
  const float* aw_b  = (const float*)d_in[29];
  const float* val_w = (const float*)d_in[30];
  const float* val_b = (const float*)d_in[31];
  const float* outp_w = (const float*)d_in[32];
  const float* outp_b = (const float*)d_in[33];
  const float* ffn_w1 = (const float*)d_in[34];
  const float* ffn_b1 = (const float*)d_in[35];
  const float* ffn_w2 = (const float*)d_in[36];
  const float* ffn_b2 = (const float*)d_in[37];

  // bf16 weight region offsets (shorts)
  const long W_G0=0, W_G1=131072, W_QS0=196608, W_QS1=262144, W_SAIN=327680,
             W_SAOUT=1507328, W_OFFAW=1900544, W_VAL=2195456,
             W_OUTP=2588672, W_FFN1=2981888, W_FFN2=4554752, W_SRC=6127616;

  char* ws = (char*)d_ws;
  short* wbf    = (short*)(ws + 0);
  short* srcbf  = wbf + W_SRC;
  short* sinebf = (short*)(ws + 70975488);
  short* ghbf   = (short*)(ws + 75890688);
  float* rawq   = (float*)(ws + 78348288);
  float* out    = (float*)(ws + 83263488);
  short* qcat   = (short*)(ws + 88178688);    // [9600][256]: rows 0..4799 = qbf, 4800.. = outbf
  short* qbf    = qcat;
  short* outbf  = qcat + (long)MROW*DM;
  short* t1bf   = (short*)(ws + 93093888);
  float* qpos   = (float*)(ws + 95551488);
  short* qkbf   = (short*)(ws + 100466688);   // [4800][512]
  short* vbf    = (short*)(ws + 105381888);   // [4800][256]
  short* attnbf = (short*)(ws + 107839488);
  float* tmpf   = (float*)(ws + 110297088);
  short* caqb   = (short*)(ws + 115212288);
  float* offaw  = (float*)(ws + 117669888);   // [4800][192]
  int2*  sIdx   = (int2*) (ws + 121356288);
  float2* sWgt  = (float2*)(ws + 125042688);
  short* cabf   = (short*)(ws + 128729088);
  short* ffnhbf = (short*)(ws + 131186688);
  float* refin  = (float*)(ws + 141017088);
  short* valbf  = (short*)(ws + 141132288);

  const bool VAL_ALL = ws_size >= 493453824ull;
  const int ldv = VAL_ALL ? 1536 : 256;

  CvtPtrs cp;
  cp.p[0]=grid_w0; cp.p[1]=grid_w1; cp.p[2]=qs_w0; cp.p[3]=qs_w1; cp.p[4]=sa_in_w;
  cp.p[5]=sa_out_w; cp.p[6]=off_w; cp.p[7]=aw_w; cp.p[8]=val_w; cp.p[9]=outp_w;
  cp.p[10]=ffn_w1; cp.p[11]=ffn_w2; cp.p[12]=src;
  cvt_all_kernel<<<dim3(34656), dim3(256), 0, stream>>>(cp, wbf);

  ew0_kernel<<<dim3(1200), dim3(256), 0, stream>>>(tgt, out, outbf);
  init_ref_kernel<<<dim3(MROW), dim3(256), 0, stream>>>(seg, dur, valid, sinebf, refin);

  // raw_qpos = MLP2(sine; grid)
  g64(stream, 1, sinebf, wbf + W_G0, grid_b0, nullptr, nullptr, ghbf, nullptr, MROW, 256, 512, 256);
  g64(stream, 0, ghbf,   wbf + W_G1, grid_b1, nullptr, rawq, nullptr, nullptr, MROW, 256, 256, 256);

  if (VAL_ALL) {
    gemm128<<<dim3(SROW/128, 12), dim3(256), 0, stream>>>(
        srcbf, wbf + W_VAL, val_b, valbf, SROW, 1536, 256, 1536, pmask);
  }

  for (int l = 0; l < NLAY; ++l) {
    g64(stream, 1, outbf, wbf + W_QS0, qs_b0, nullptr, nullptr, t1bf, nullptr, MROW, 256, 256, 256);
    g64(stream, 2, t1bf,  wbf + W_QS1, qs_b1, nullptr, qpos, qbf, nullptr, MROW, 256, 256, 256,
        rawq, out);
    g64(stream, 3, qcat, wbf + W_SAIN + (long)l*196608, sa_in_b + l*768, nullptr,
        nullptr, qkbf, vbf, 2*MROW, 768, 256, 0);
    attn_mfma<<<dim3(256), dim3(256), 0, stream>>>(qkbf, vbf, attnbf);
    g64(stream, 0, attnbf, wbf + W_SAOUT + (long)l*65536, sa_out_b + l*256, nullptr,
        tmpf, nullptr, nullptr, MROW, 256, 256, 256);
    ln_kernel<<<dim3(MROW), dim3(256), 0, stream>>>(out, tmpf, n1_g + l*256, n1_b + l*256,
                                                    out, outbf, qpos, caqb);
    g64(stream, 4, caqb, wbf + W_OFFAW + (long)l*49152, off_b + l*96, aw_b + l*96,
        offaw, nullptr, nullptr, MROW, 192, 256, 192);
    prep_kernel<<<dim3(150), dim3(256), 0, stream>>>(offaw, refin, tlens, lstart, sIdx, sWgt);
    if (!VAL_ALL) {
      gemm128<<<dim3(SROW/128, 2), dim3(256), 0, stream>>>(
          srcbf, wbf + W_VAL + (long)l*65536, val_b + l*256, valbf, SROW, 256, 256, 256, pmask);
    }
    sample_kernel<<<dim3(MROW), dim3(256), 0, stream>>>(
        valbf + (VAL_ALL ? (long)l*256 : 0), ldv, sIdx, sWgt, cabf);
    g64(stream, 0, cabf, wbf + W_OUTP + (long)l*65536, outp_b + l*256, nullptr,
        tmpf, nullptr, nullptr, MROW, 256, 256, 256);
    ln_kernel<<<dim3(MROW), dim3(256), 0, stream>>>(out, tmpf, n2_g + l*256, n2_b + l*256,
                                                    out, outbf, nullptr, nullptr);
    g64(stream, 1, outbf, wbf + W_FFN1 + (long)l*262144, ffn_b1 + l*1024, nullptr,
        nullptr, ffnhbf, nullptr, MROW, 1024, 256, 1024);
    g64(stream, 0, ffnhbf, wbf + W_FFN2 + (long)l*262144, ffn_b2 + l*256, nullptr,
        tmpf, nullptr, nullptr, MROW, 256, 1024, 256);
    float* of = (l == NLAY-1) ? (float*)d_out : out;
    ln_kernel<<<dim3(MROW), dim3(256), 0, stream>>>(out, tmpf, n3_g + l*256, n3_b + l*256,
                                                    of, outbf, nullptr, nullptr);
  }
}

// Round 3
// 1260.957 us; speedup vs baseline: 2.1196x; 1.0771x over previous
//
#include <hip/hip_runtime.h>
#include <cstdint>

#define NB   16
#define LQN  300
#define DM   256
#define NH   8
#define DH   32
#define NLV  3
#define DFFN 1024
#define NLAY 6
#define TT   7168
#define MROW (NB*LQN)   // 4800
#define SROW (NB*TT)    // 114688

typedef __attribute__((ext_vector_type(8))) short bf16x8;
typedef __attribute__((ext_vector_type(4))) float f32x4;

__device__ __forceinline__ float bf2f(short u) {
  unsigned x = ((unsigned)(unsigned short)u) << 16;
  return __builtin_bit_cast(float, x);
}
__device__ __forceinline__ short f2bf(float f) {
  unsigned u = __builtin_bit_cast(unsigned, f);
  u += 0x7fffu + ((u >> 16) & 1u);   // RNE
  return (short)(u >> 16);
}
__device__ __forceinline__ void load_lds16(const void* g, void* l) {
  __builtin_amdgcn_global_load_lds(
      (const __attribute__((address_space(1))) unsigned int*)g,
      (__attribute__((address_space(3))) unsigned int*)l, 16, 0, 0);
}
#define MFMA(a,b,c) __builtin_amdgcn_mfma_f32_16x16x32_bf16((a),(b),(c),0,0,0)

// ---------------- weight/src fp32->bf16 conversion ----------------
struct CvtPtrs { const float* p[13]; };

__global__ __launch_bounds__(256)
void cvt_all_kernel(CvtPtrs ptrs, short* __restrict__ dst)
{
  const long gid = (long)blockIdx.x*256 + threadIdx.x;  // float4 units
  const long cums[14] = {0,32768,49152,65536,81920,376832,475136,512000,
                         548864,647168,745472,1138688,1531904,8871936};
  int s = 0;
  #pragma unroll
  for (int i = 1; i < 13; ++i) s += (gid >= cums[i]) ? 1 : 0;
  const long rel = gid - cums[s];
  const float4 v = ((const float4*)ptrs.p[s])[rel];
  long dstIdx = gid;
  if (s == 6) { const long l = rel/6144, w = rel%6144; dstIdx = 475136 + l*12288 + w; }
  else if (s == 7) { const long l = rel/6144, w = rel%6144; dstIdx = 475136 + l*12288 + 6144 + w; }
  ((short4*)dst)[dstIdx] = make_short4(f2bf(v.x), f2bf(v.y), f2bf(v.z), f2bf(v.w));
}

// ---------------- GEMM 128x128: Cb = bf16(A@B^T + bias), rowmask ----------------
// T2 XOR-swizzled LDS (pre-swizzled global source, rule #21) + 2-phase counted-vmcnt.
__global__ __launch_bounds__(256)
void gemm128(const short* __restrict__ A, const short* __restrict__ B,
             const float* __restrict__ bias, short* __restrict__ Cb,
             int M, int N, int K, int ldc,
             const unsigned char* __restrict__ rowmask)
{
  __shared__ short As[2][128*64];
  __shared__ short Bs[2][128*64];
  const int tid  = threadIdx.x;
  const int wid  = tid >> 6;
  const int lane = tid & 63;
  const int wr = wid >> 1, wc = wid & 1;
  const int fr = lane & 15, fq = lane >> 4;
  const int bm = blockIdx.x, bn = blockIdx.y;
  const int lrow = lane >> 3;                 // 0..7
  const int schk = ((lane & 7) ^ lrow) * 8;   // swizzled source chunk (shorts)

  int arow[4], brow[4];
  #pragma unroll
  for (int i = 0; i < 4; ++i) {
    const int srow = wid*8 + lrow;
    int r  = bm*128 + i*32 + srow; arow[i] = r  < M ? r  : M-1;
    int rb = bn*128 + i*32 + srow; brow[i] = rb < N ? rb : N-1;
  }
  const int nk = K >> 6;
  f32x4 acc[4][4] = {};

  auto stg = [&](int kt, int bsel) {
    const int k0 = kt << 6;
    #pragma unroll
    for (int i = 0; i < 4; ++i) {
      load_lds16(A + (long)arow[i]*K + k0 + schk, &As[bsel][(i*32 + wid*8)*64]);
      load_lds16(B + (long)brow[i]*K + k0 + schk, &Bs[bsel][(i*32 + wid*8)*64]);
    }
  };

  stg(0, 0);
  for (int t = 0; t < nk; ++t) {
    const int cur = t & 1;
    if (t + 1 < nk) {
      stg(t + 1, cur ^ 1);
      asm volatile("s_waitcnt vmcnt(8)" ::: "memory");
    } else {
      asm volatile("s_waitcnt vmcnt(0)" ::: "memory");
    }
    __builtin_amdgcn_s_barrier();
    __builtin_amdgcn_sched_barrier(0);
    #pragma unroll
    for (int kk = 0; kk < 64; kk += 32) {
      bf16x8 af[4], bfr[4];
      #pragma unroll
      for (int mi = 0; mi < 4; ++mi)
        af[mi] = *(const bf16x8*)&As[cur][(wr*64 + mi*16 + fr)*64 + (((kk>>3)+fq) ^ (fr&7))*8];
      #pragma unroll
      for (int ni = 0; ni < 4; ++ni)
        bfr[ni] = *(const bf16x8*)&Bs[cur][(wc*64 + ni*16 + fr)*64 + (((kk>>3)+fq) ^ (fr&7))*8];
      #pragma unroll
      for (int mi = 0; mi < 4; ++mi)
        #pragma unroll
        for (int ni = 0; ni < 4; ++ni)
          acc[mi][ni] = MFMA(af[mi], bfr[ni], acc[mi][ni]);
    }
    __builtin_amdgcn_s_barrier();
  }

  #pragma unroll
  for (int mi = 0; mi < 4; ++mi) {
    #pragma unroll
    for (int r = 0; r < 4; ++r) {
      const int grow = bm*128 + wr*64 + mi*16 + fq*4 + r;
      if (grow >= M) continue;
      const float msc = rowmask ? (rowmask[grow] ? 0.0f : 1.0f) : 1.0f;
      #pragma unroll
      for (int ni = 0; ni < 4; ++ni) {
        const int gcol = bn*128 + wc*64 + ni*16 + fr;
        if (gcol >= N) continue;
        const float v = (acc[mi][ni][r] + bias[gcol]) * msc;
        Cb[(long)grow*ldc + gcol] = f2bf(v);
      }
    }
  }
}

// ---------------- GEMM 64x64 tile, A[M,K] @ B[N,K]^T + bias ----------------
// EPI: 0 plain, 1 relu->Cb, 2 qpos, 3 sain-route, 4 two-bias->Cf
template<int EPI>
__global__ __launch_bounds__(256)
void gemm64(const short* __restrict__ A, const short* __restrict__ B,
            const float* __restrict__ bias, const float* __restrict__ bias2,
            float* __restrict__ Cf, short* __restrict__ Cb, short* __restrict__ Cb2,
            int M, int N, int K, int ldc,
            const float* __restrict__ rawq, const float* __restrict__ resid)
{
  __shared__ short As[2][64*64];
  __shared__ short Bs[2][64*64];
  const int tid = threadIdx.x, wid = tid >> 6, lane = tid & 63;
  const int wr = wid >> 1, wc = wid & 1;
  const int fr = lane & 15, fq = lane >> 4;
  const int bm = blockIdx.x, bn = blockIdx.y;
  const int lrow = lane >> 3;
  const int schk = ((lane & 7) ^ lrow) * 8;
  const int nk = K >> 6;

  f32x4 acc[2][2] = {};

  auto stg = [&](int kt, int bsel) {
    const int k0 = kt << 6;
    #pragma unroll
    for (int i = 0; i < 2; ++i) {
      const int rr = wid*16 + i*8 + lrow;
      load_lds16(A + (long)(bm*64 + rr)*K + k0 + schk, &As[bsel][(wid*16 + i*8)*64]);
      load_lds16(B + (long)(bn*64 + rr)*K + k0 + schk, &Bs[bsel][(wid*16 + i*8)*64]);
    }
  };

  stg(0, 0);
  for (int t = 0; t < nk; ++t) {
    const int cur = t & 1;
    if (t + 1 < nk) {
      stg(t + 1, cur ^ 1);
      asm volatile("s_waitcnt vmcnt(4)" ::: "memory");
    } else {
      asm volatile("s_waitcnt vmcnt(0)" ::: "memory");
    }
    __builtin_amdgcn_s_barrier();
    __builtin_amdgcn_sched_barrier(0);
    #pragma unroll
    for (int kk = 0; kk < 64; kk += 32) {
      bf16x8 af[2], bv[2];
      #pragma unroll
      for (int mi = 0; mi < 2; ++mi)
        af[mi] = *(const bf16x8*)&As[cur][(wr*32 + mi*16 + fr)*64 + (((kk>>3)+fq) ^ (fr&7))*8];
      #pragma unroll
      for (int ni = 0; ni < 2; ++ni)
        bv[ni] = *(const bf16x8*)&Bs[cur][(wc*32 + ni*16 + fr)*64 + (((kk>>3)+fq) ^ (fr&7))*8];
      #pragma unroll
      for (int mi = 0; mi < 2; ++mi)
        #pragma unroll
        for (int ni = 0; ni < 2; ++ni)
          acc[mi][ni] = MFMA(af[mi], bv[ni], acc[mi][ni]);
    }
    __builtin_amdgcn_s_barrier();
  }

  #pragma unroll
  for (int mi = 0; mi < 2; ++mi) {
    #pragma unroll
    for (int r = 0; r < 4; ++r) {
      const int grow = bm*64 + wr*32 + mi*16 + fq*4 + r;
      #pragma unroll
      for (int ni = 0; ni < 2; ++ni) {
        const int gcol = bn*64 + wc*32 + ni*16 + fr;
        float v = acc[mi][ni][r];
        if (EPI == 4) v += (gcol < 96) ? bias[gcol] : bias2[gcol-96];
        else v += bias[gcol];
        const long off = (long)grow*ldc + gcol;
        if (EPI == 0) {
          if (Cf) Cf[off] = v;
          if (Cb) Cb[off] = f2bf(v);
        } else if (EPI == 1) {
          Cb[off] = f2bf(fmaxf(v, 0.0f));
        } else if (EPI == 2) {
          const float qp = v * rawq[off];
          Cf[off] = qp;
          Cb[off] = f2bf(resid[off] + qp);
        } else if (EPI == 3) {
          if (grow < MROW) { if (gcol < 512) Cb[(long)grow*512 + gcol] = f2bf(v); }
          else             { if (gcol >= 512) Cb2[(long)(grow-MROW)*256 + gcol-512] = f2bf(v); }
        } else if (EPI == 4) {
          Cf[off] = v;
        }
      }
    }
  }
}

// ---------------- out = tgt (f32 + bf16 copies) ----------------
__global__ __launch_bounds__(256)
void ew0_kernel(const float* __restrict__ tgt, float* __restrict__ out, short* __restrict__ outbf)
{
  const long i = (long)blockIdx.x*256 + threadIdx.x;
  const float4 v = ((const float4*)tgt)[i];
  ((float4*)out)[i] = v;
  ((short4*)outbf)[i] = make_short4(f2bf(v.x), f2bf(v.y), f2bf(v.z), f2bf(v.w));
}

// ---------------- ref / ref_in / sine embedding ----------------
__global__ __launch_bounds__(256)
void init_ref_kernel(const float* __restrict__ seg, const float* __restrict__ dur,
                     const float* __restrict__ valid,
                     short* __restrict__ sinebf, float* __restrict__ refin)
{
  const int m = blockIdx.x;
  const int n = m / LQN;
  const int t = threadIdx.x;
  const float c = seg[(long)m*2 + 0];
  const float w = __expf(seg[(long)m*2 + 1]);
  const float e = (float)(t & ~1) * (1.0f/256.0f);
  const float invdim = __expf(-e * 9.2103403719761836f);
  const float twopi = 6.2831853071795864f;
  const float a0 = c * twopi * invdim;
  const float a1 = w * twopi * invdim;
  const float v0 = (t & 1) ? cosf(a0) : sinf(a0);
  const float v1 = (t & 1) ? cosf(a1) : sinf(a1);
  sinebf[(long)m*512 + t]       = f2bf(v0);
  sinebf[(long)m*512 + 256 + t] = f2bf(v1);
  if (t < 6) {
    const int l = t >> 1, cc = t & 1;
    const float rv = cc ? w : c;
    refin[(long)m*6 + l*2 + cc] = rv / dur[n] * valid[n*NLV + l];
  }
}

// ---------------- MFMA attention ----------------
#define KPAD 320
#define KSTR 40
#define VSTR 328
#define PSTR 328

__global__ __launch_bounds__(256)
void attn_mfma(const short* __restrict__ qk, const short* __restrict__ vv,
               short* __restrict__ outb)
{
  __shared__ short Kl[KPAD*KSTR];
  __shared__ short Vt[DH*VSTR];
  __shared__ short Pl[4][16*PSTR];
  const int b = blockIdx.x;
  const int half = b & 1, h = (b >> 1) & 7, n = b >> 4;
  const int tid = threadIdx.x, wid = tid >> 6, lane = tid & 63;
  const int fr = lane & 15, fq = lane >> 4;

  const short* qkn = qk + (long)n*LQN*512;
  const short* vn  = vv + (long)n*LQN*256;

  for (int t = tid; t < KPAD*4; t += 256) {
    const int r = t >> 2, c = t & 3;
    bf16x8 kv = {}, vw = {};
    if (r < LQN) {
      kv = *(const bf16x8*)(qkn + (long)r*512 + 256 + h*32 + c*8);
      vw = *(const bf16x8*)(vn  + (long)r*256 + h*32 + c*8);
    }
    *(bf16x8*)&Kl[r*KSTR + c*8] = kv;
    #pragma unroll
    for (int j = 0; j < 8; ++j) Vt[(c*8+j)*VSTR + r] = vw[j];
  }
  for (int t = tid; t < 4*16*24; t += 256) {
    const int w = t / (16*24), rr = (t / 24) & 15, cc = t % 24;
    Pl[w][rr*PSTR + 304 + cc] = 0;
  }
  __syncthreads();

  const int tlo = half ? 10 : 0, thi = half ? 19 : 10;
  const float scl2 = 0.17677669529663687f * 1.4426950408889634f;

  for (int qt = tlo + wid; qt < thi; qt += 4) {
    const int q0 = qt * 16;
    const int qrow = min(q0 + fr, LQN-1);
    const bf16x8 qf = *(const bf16x8*)(qkn + (long)qrow*512 + h*32 + fq*8);
    f32x4 s[19];
    #pragma unroll
    for (int t = 0; t < 19; ++t) {
      const bf16x8 kf = *(const bf16x8*)&Kl[(t*16+fr)*KSTR + fq*8];
      s[t] = MFMA(qf, kf, ((f32x4){0.f,0.f,0.f,0.f}));
    }
    float mx[4] = {-3e38f,-3e38f,-3e38f,-3e38f};
    #pragma unroll
    for (int t = 0; t < 19; ++t) {
      const bool valid = (t < 18) || (fr < 12);
      #pragma unroll
      for (int r = 0; r < 4; ++r) if (valid) mx[r] = fmaxf(mx[r], s[t][r]);
    }
    #pragma unroll
    for (int r = 0; r < 4; ++r) {
      #pragma unroll
      for (int o = 1; o < 16; o <<= 1) mx[r] = fmaxf(mx[r], __shfl_xor(mx[r], o));
      mx[r] *= scl2;
    }
    float l[4] = {0.f,0.f,0.f,0.f};
    #pragma unroll
    for (int t = 0; t < 19; ++t) {
      const bool valid = (t < 18) || (fr < 12);
      #pragma unroll
      for (int r = 0; r < 4; ++r) {
        const float p = valid ? exp2f(s[t][r]*scl2 - mx[r]) : 0.0f;
        l[r] += p;
        Pl[wid][(fq*4+r)*PSTR + t*16 + fr] = f2bf(p);
      }
    }
    #pragma unroll
    for (int r = 0; r < 4; ++r) {
      #pragma unroll
      for (int o = 1; o < 16; o <<= 1) l[r] += __shfl_xor(l[r], o);
    }
    f32x4 o0 = {}, o1 = {};
    #pragma unroll
    for (int ck = 0; ck < 10; ++ck) {
      const bf16x8 pf = *(const bf16x8*)&Pl[wid][fr*PSTR + ck*32 + fq*8];
      const bf16x8 v0 = *(const bf16x8*)&Vt[fr*VSTR + ck*32 + fq*8];
      const bf16x8 v1 = *(const bf16x8*)&Vt[(16+fr)*VSTR + ck*32 + fq*8];
      o0 = MFMA(pf, v0, o0);
      o1 = MFMA(pf, v1, o1);
    }
    #pragma unroll
    for (int r = 0; r < 4; ++r) {
      const int qq = q0 + fq*4 + r;
      if (qq < LQN) {
        const float inv = 1.0f / l[r];
        outb[((long)(n*LQN+qq))*256 + h*32 + fr]      = f2bf(o0[r]*inv);
        outb[((long)(n*LQN+qq))*256 + h*32 + 16 + fr] = f2bf(o1[r]*inv);
      }
    }
  }
}

// ---------------- residual + LayerNorm ----------------
__global__ __launch_bounds__(256)
void ln_kernel(const float* __restrict__ resid, const float* __restrict__ delta,
               const float* __restrict__ g, const float* __restrict__ b,
               float* __restrict__ of, short* __restrict__ ob,
               const float* __restrict__ qpos, short* __restrict__ caqb)
{
  const int m = blockIdx.x, c = threadIdx.x;
  const long idx = (long)m*DM + c;
  const float x = resid[idx] + delta[idx];
  float s = x, s2 = x*x;
  #pragma unroll
  for (int o = 1; o < 64; o <<= 1) { s += __shfl_xor(s, o); s2 += __shfl_xor(s2, o); }
  __shared__ float rs[4], rs2[4];
  const int w = c >> 6;
  if ((c & 63) == 0) { rs[w] = s; rs2[w] = s2; }
  __syncthreads();
  s  = rs[0]+rs[1]+rs[2]+rs[3];
  s2 = rs2[0]+rs2[1]+rs2[2]+rs2[3];
  const float mean = s * (1.0f/DM);
  const float var  = s2 * (1.0f/DM) - mean*mean;
  const float y = (x - mean) * rsqrtf(var + 1e-5f) * g[c] + b[c];
  of[idx] = y;
  if (ob) ob[idx] = f2bf(y);
  if (qpos) caqb[idx] = f2bf(y + qpos[idx]);
}

// ---------------- sampling: fused prep (softmax+bilinear) + gather-MAC ----------------
__global__ __launch_bounds__(256)
void sample_kernel(const short* __restrict__ val, int ldv,
                   const float* __restrict__ offaw, const float* __restrict__ refin,
                   const int* __restrict__ tlens, const int* __restrict__ lstart,
                   short* __restrict__ cab)
{
  const int m = blockIdx.x;
  const int n = m / LQN;
  const int tid = threadIdx.x;
  __shared__ int2  lI[96];
  __shared__ float2 lW[96];
  if ((tid & 31) == 0) {
    const int h = tid >> 5;
    const float* row = offaw + (long)m*192;
    float aw[12];
    float mx = -1e30f;
    #pragma unroll
    for (int lp = 0; lp < 12; ++lp) { aw[lp] = row[96 + h*12 + lp]; mx = fmaxf(mx, aw[lp]); }
    float sum = 0.0f;
    #pragma unroll
    for (int lp = 0; lp < 12; ++lp) { aw[lp] = __expf(aw[lp]-mx); sum += aw[lp]; }
    const float invs = 1.0f / sum;
    #pragma unroll
    for (int lp = 0; lp < 12; ++lp) {
      const int l = lp >> 2;
      const int tli = tlens[l];
      const float off = row[h*12 + lp];
      const float loc = refin[(long)m*6 + l*2] + off * 0.25f * refin[(long)m*6 + l*2 + 1] * 0.5f;
      const float x = loc * (float)tli - 0.5f;
      const float x0f = floorf(x);
      const float f = x - x0f;
      const int x0 = (int)x0f;
      const int i0 = lstart[l] + min(max(x0,   0), tli-1);
      const int i1 = lstart[l] + min(max(x0+1, 0), tli-1);
      const float wgt = aw[lp]*invs;
      const float w0 = (x0   >= 0 && x0   < tli) ? wgt*(1.0f-f) : 0.0f;
      const float w1 = (x0+1 >= 0 && x0+1 < tli) ? wgt*f        : 0.0f;
      lI[h*12 + lp] = make_int2(i0, i1);
      lW[h*12 + lp] = make_float2(w0, w1);
    }
  }
  __syncthreads();
  const int h = tid >> 5;
  const short* vb = val + (long)n*TT*ldv;
  float acc = 0.0f;
  #pragma unroll
  for (int lp = 0; lp < 12; ++lp) {
    const int e = h*12 + lp;
    const int2 ii = lI[e];
    const float2 ww = lW[e];
    acc += ww.x * bf2f(vb[(long)ii.x*ldv + tid]) + ww.y * bf2f(vb[(long)ii.y*ldv + tid]);
  }
  cab[(long)m*DM + tid] = f2bf(acc);
}

// ---------------- host side ----------------
static inline void g64(hipStream_t st, int epi, const short* A, const short* B,
                       const float* bias, const float* bias2,
                       float* Cf, short* Cb, short* Cb2,
                       int M, int N, int K, int ldc,
                       const float* rawq = nullptr, const float* resid = nullptr)
{
  dim3 g(M/64, N/64), blk(256);
  switch (epi) {
    case 0: gemm64<0><<<g,blk,0,st>>>(A,B,bias,bias2,Cf,Cb,Cb2,M,N,K,ldc,rawq,resid); break;
    case 1: gemm64<1><<<g,blk,0,st>>>(A,B,bias,bias2,Cf,Cb,Cb2,M,N,K,ldc,rawq,resid); break;
    case 2: gemm64<2><<<g,blk,0,st>>>(A,B,bias,bias2,Cf,Cb,Cb2,M,N,K,ldc,rawq,resid); break;
    case 3: gemm64<3><<<g,blk,0,st>>>(A,B,bias,bias2,Cf,Cb,Cb2,M,N,K,ldc,rawq,resid); break;
    default:gemm64<4><<<g,blk,0,st>>>(A,B,bias,bias2,Cf,Cb,Cb2,M,N,K,ldc,rawq,resid); break;
  }
}

extern "C" void kernel_launch(void* const* d_in, const int* in_sizes, int n_in,
                              void* d_out, int out_size, void* d_ws, size_t ws_size,
                              hipStream_t stream)
{
  const float* tgt    = (const float*)d_in[0];
  const float* seg    = (const float*)d_in[1];
  const float* dur    = (const float*)d_in[2];
  const float* src    = (const float*)d_in[3];
  const int*   tlens  = (const int*)d_in[4];
  const int*   lstart = (const int*)d_in[5];
  const float* valid  = (const float*)d_in[6];
  const unsigned char* pmask = (const unsigned char*)d_in[7];
  const float* grid_w0 = (const float*)d_in[8];
  const float* grid_b0 = (const float*)d_in[9];
  const float* grid_w1 = (const float*)d_in[10];
  const float* grid_b1 = (const float*)d_in[11];
  const float* qs_w0 = (const float*)d_in[12];
  const float* qs_b0 = (const float*)d_in[13];
  const float* qs_w1 = (const float*)d_in[14];
  const float* qs_b1 = (const float*)d_in[15];
  const float* sa_in_w  = (const float*)d_in[16];
  const float* sa_in_b  = (const float*)d_in[17];
  const float* sa_out_w = (const float*)d_in[18];
  const float* sa_out_b = (const float*)d_in[19];
  const float* n1_g = (const float*)d_in[20];
  const float* n1_b = (const float*)d_in[21];
  const float* n2_g = (const float*)d_in[22];
  const float* n2_b = (const float*)d_in[23];
  const float* n3_g = (const float*)d_in[24];
  const float* n3_b = (const float*)d_in[25];
  const float* off_w = (const float*)d_in[26];
  const float* off_b = (const float*)d_in[27];
  const float* aw_w  = (const float*)d_in[28];
  const float* aw_b  = (const float*)d_in[29];
  const float* val_w = (const float*)d_in[30];
  const float* val_b = (const float*)d_in[31];
  const float* outp_w = (const float*)d_in[32];
  const float* outp_b = (const float*)d_in[33];
  const float* ffn_w1 = (const float*)d_in[34];
  const float* ffn_b1 = (const float*)d_in[35];
  const float* ffn_w2 = (const float*)d_in[36];
  const float* ffn_b2 = (const float*)d_in[37];

  const long W_G0=0, W_G1=131072, W_QS0=196608, W_QS1=262144, W_SAIN=327680,
             W_SAOUT=1507328, W_OFFAW=1900544, W_VAL=2195456,
             W_OUTP=2588672, W_FFN1=2981888, W_FFN2=4554752, W_SRC=6127616;

  char* ws = (char*)d_ws;
  short* wbf    = (short*)(ws + 0);
  short* srcbf  = wbf + W_SRC;
  short* sinebf = (short*)(ws + 70975488);
  short* ghbf   = (short*)(ws + 75890688);
  float* rawq   = (float*)(ws + 78348288);
  float* out    = (float*)(ws + 83263488);
  short* qcat   = (short*)(ws + 88178688);
  short* qbf    = qcat;
  short* outbf  = qcat + (long)MROW*DM;
  short* t1bf   = (short*)(ws + 93093888);
  float* qpos   = (float*)(ws + 95551488);
  short* qkbf   = (short*)(ws + 100466688);
  short* vbf    = (short*)(ws + 105381888);
  short* attnbf = (short*)(ws + 107839488);
  float* tmpf   = (float*)(ws + 110297088);
  short* caqb   = (short*)(ws + 115212288);
  float* offaw  = (float*)(ws + 117669888);
  short* cabf   = (short*)(ws + 128729088);
  short* ffnhbf = (short*)(ws + 131186688);
  float* refin  = (float*)(ws + 141017088);
  short* valbf  = (short*)(ws + 141132288);

  const bool VAL_ALL = ws_size >= 493453824ull;
  const int ldv = VAL_ALL ? 1536 : 256;

  CvtPtrs cp;
  cp.p[0]=grid_w0; cp.p[1]=grid_w1; cp.p[2]=qs_w0; cp.p[3]=qs_w1; cp.p[4]=sa_in_w;
  cp.p[5]=sa_out_w; cp.p[6]=off_w; cp.p[7]=aw_w; cp.p[8]=val_w; cp.p[9]=outp_w;
  cp.p[10]=ffn_w1; cp.p[11]=ffn_w2; cp.p[12]=src;
  cvt_all_kernel<<<dim3(34656), dim3(256), 0, stream>>>(cp, wbf);

  ew0_kernel<<<dim3(1200), dim3(256), 0, stream>>>(tgt, out, outbf);
  init_ref_kernel<<<dim3(MROW), dim3(256), 0, stream>>>(seg, dur, valid, sinebf, refin);

  g64(stream, 1, sinebf, wbf + W_G0, grid_b0, nullptr, nullptr, ghbf, nullptr, MROW, 256, 512, 256);
  g64(stream, 0, ghbf,   wbf + W_G1, grid_b1, nullptr, rawq, nullptr, nullptr, MROW, 256, 256, 256);

  if (VAL_ALL) {
    gemm128<<<dim3(SROW/128, 12), dim3(256), 0, stream>>>(
        srcbf, wbf + W_VAL, val_b, valbf, SROW, 1536, 256, 1536, pmask);
  }

  for (int l = 0; l < NLAY; ++l) {
    g64(stream, 1, outbf, wbf + W_QS0, qs_b0, nullptr, nullptr, t1bf, nullptr, MROW, 256, 256, 256);
    g64(stream, 2, t1bf,  wbf + W_QS1, qs_b1, nullptr, qpos, qbf, nullptr, MROW, 256, 256, 256,
        rawq, out);
    g64(stream, 3, qcat, wbf + W_SAIN + (long)l*196608, sa_in_b + l*768, nullptr,
        nullptr, qkbf, vbf, 2*MROW, 768, 256, 0);
    attn_mfma<<<dim3(256), dim3(256), 0, stream>>>(qkbf, vbf, attnbf);
    g64(stream, 0, attnbf, wbf + W_SAOUT + (long)l*65536, sa_out_b + l*256, nullptr,
        tmpf, nullptr, nullptr, MROW, 256, 256, 256);
    ln_kernel<<<dim3(MROW), dim3(256), 0, stream>>>(out, tmpf, n1_g + l*256, n1_b + l*256,
                                                    out, outbf, qpos, caqb);
    g64(stream, 4, caqb, wbf + W_OFFAW + (long)l*49152, off_b + l*96, aw_b + l*96,
        offaw, nullptr, nullptr, MROW, 192, 256, 192);
    if (!VAL_ALL) {
      gemm128<<<dim3(SROW/128, 2), dim3(256), 0, stream>>>(
          srcbf, wbf + W_VAL + (long)l*65536, val_b + l*256, valbf, SROW, 256, 256, 256, pmask);
    }
    sample_kernel<<<dim3(MROW), dim3(256), 0, stream>>>(
        valbf + (VAL_ALL ? (long)l*256 : 0), ldv, offaw, refin, tlens, lstart, cabf);
    g64(stream, 0, cabf, wbf + W_OUTP + (long)l*65536, outp_b + l*256, nullptr,
        tmpf, nullptr, nullptr, MROW, 256, 256, 256);
    ln_kernel<<<dim3(MROW), dim3(256), 0, stream>>>(out, tmpf, n2_g + l*256, n2_b + l*256,
                                                    out, outbf, nullptr, nullptr);
    g64(stream, 1, outbf, wbf + W_FFN1 + (long)l*262144, ffn_b1 + l*1024, nullptr,
        nullptr, ffnhbf, nullptr, MROW, 1024, 256, 1024);
    g64(stream, 0, ffnhbf, wbf + W_FFN2 + (long)l*262144, ffn_b2 + l*256, nullptr,
        tmpf, nullptr, nullptr, MROW, 256, 1024, 256);
    float* of = (l == NLAY-1) ? (float*)d_out : out;
    ln_kernel<<<dim3(MROW), dim3(256), 0, stream>>>(out, tmpf, n3_g + l*256, n3_b + l*256,
                                                    of, outbf, nullptr, nullptr);
  }
}

// Round 6
// 1051.953 us; speedup vs baseline: 2.5407x; 1.1987x over previous
//
#include <hip/hip_runtime.h>
#include <cstdint>

#define NB   16
#define LQN  300
#define DM   256
#define NH   8
#define DH   32
#define NLV  3
#define DFFN 1024
#define NLAY 6
#define TT   7168
#define MROW (NB*LQN)   // 4800
#define SROW (NB*TT)    // 114688

typedef __attribute__((ext_vector_type(8))) short bf16x8;
typedef __attribute__((ext_vector_type(4))) float f32x4;

__device__ __forceinline__ float bf2f(short u) {
  unsigned x = ((unsigned)(unsigned short)u) << 16;
  return __builtin_bit_cast(float, x);
}
__device__ __forceinline__ short f2bf(float f) {
  unsigned u = __builtin_bit_cast(unsigned, f);
  u += 0x7fffu + ((u >> 16) & 1u);   // RNE
  return (short)(u >> 16);
}
__device__ __forceinline__ void load_lds16(const void* g, void* l) {
  __builtin_amdgcn_global_load_lds(
      (const __attribute__((address_space(1))) unsigned int*)g,
      (__attribute__((address_space(3))) unsigned int*)l, 16, 0, 0);
}
#define MFMA(a,b,c) __builtin_amdgcn_mfma_f32_16x16x32_bf16((a),(b),(c),0,0,0)

// ---------------- weight fp32->bf16 conversion (weights only; src stays f32) ----------------
struct CvtPtrs { const float* p[12]; };

__global__ __launch_bounds__(256)
void cvt_all_kernel(CvtPtrs ptrs, short* __restrict__ dst)
{
  const long gid = (long)blockIdx.x*256 + threadIdx.x;  // float4 units
  const long cums[13] = {0,32768,49152,65536,81920,376832,475136,512000,
                         548864,647168,745472,1138688,1531904};
  int s = 0;
  #pragma unroll
  for (int i = 1; i < 12; ++i) s += (gid >= cums[i]) ? 1 : 0;
  const long rel = gid - cums[s];
  const float4 v = ((const float4*)ptrs.p[s])[rel];
  long dstIdx = gid;
  if (s == 6) { const long l = rel/6144, w = rel%6144; dstIdx = 475136 + l*12288 + w; }
  else if (s == 7) { const long l = rel/6144, w = rel%6144; dstIdx = 475136 + l*12288 + 6144 + w; }
  ((short4*)dst)[dstIdx] = make_short4(f2bf(v.x), f2bf(v.y), f2bf(v.z), f2bf(v.w));
}

// ---------------- val projection: barrier-free streaming GEMM ----------------
// valbf[r][c] = bf16((sum_k src[r][k]*vw[c][k] + vb[c]) * mask(r)); B fully in padded LDS.
#define VLS 264   // padded LDS row stride (shorts); 16B-aligned, <=2-way banks

__global__ __launch_bounds__(512, 1)
void val_gemm(const float* __restrict__ src, const short* __restrict__ Bw,
              const float* __restrict__ bias, short* __restrict__ Cb,
              const unsigned char* __restrict__ rowmask)
{
  __shared__ short Bs[256*VLS];   // 135,168 B
  const int tid = threadIdx.x, wid = tid >> 6, lane = tid & 63;
  const int fr = lane & 15, fq = lane >> 4;

  // stage B [256][256] bf16 via plain ds_write (no swizzle; padded stride)
  for (int t = tid; t < 8192; t += 512) {
    const int row = t >> 5, ch = t & 31;
    const bf16x8 v = *(const bf16x8*)(Bw + row*256 + ch*8);
    *(bf16x8*)&Bs[row*VLS + ch*8] = v;
  }
  __syncthreads();

  // one 16-row src strip per wave; grid.x*8 waves == SROW/16 strips exactly
  const int rbase = (blockIdx.x*8 + wid) * 16;

  f32x4 acc[16] = {};
  bf16x8 aA, aB;

  auto loadA = [&](bf16x8& a, int ks) {
    const float* ap = src + (long)(rbase + fr)*256 + ks*32 + fq*8;
    const float4 f0 = *(const float4*)ap;
    const float4 f1 = *(const float4*)(ap + 4);
    bf16x8 t;
    t[0]=f2bf(f0.x); t[1]=f2bf(f0.y); t[2]=f2bf(f0.z); t[3]=f2bf(f0.w);
    t[4]=f2bf(f1.x); t[5]=f2bf(f1.y); t[6]=f2bf(f1.z); t[7]=f2bf(f1.w);
    a = t;
  };

  loadA(aA, 0);
  #pragma unroll
  for (int ks = 0; ks < 8; ++ks) {
    if (ks + 1 < 8) { if ((ks & 1) == 0) loadA(aB, ks + 1); else loadA(aA, ks + 1); }
    const bf16x8 a = ((ks & 1) == 0) ? aA : aB;
    #pragma unroll
    for (int nt = 0; nt < 16; ++nt) {
      const bf16x8 b = *(const bf16x8*)&Bs[(nt*16 + fr)*VLS + ks*32 + fq*8];
      acc[nt] = MFMA(a, b, acc[nt]);
    }
  }

  #pragma unroll
  for (int r = 0; r < 4; ++r) {
    const int grow = rbase + fq*4 + r;
    const float msc = rowmask[grow] ? 0.0f : 1.0f;
    #pragma unroll
    for (int nt = 0; nt < 16; ++nt) {
      const int gcol = nt*16 + fr;
      Cb[(long)grow*256 + gcol] = f2bf((acc[nt][r] + bias[gcol]) * msc);
    }
  }
}

// ---------------- GEMM 64x64 tile, A[M,K] @ B[N,K]^T + bias (R3-proven) ----------------
// EPI: 0 plain, 1 relu->Cb, 2 qpos, 3 sain-route, 4 two-bias->Cf
template<int EPI>
__global__ __launch_bounds__(256)
void gemm64(const short* __restrict__ A, const short* __restrict__ B,
            const float* __restrict__ bias, const float* __restrict__ bias2,
            float* __restrict__ Cf, short* __restrict__ Cb, short* __restrict__ Cb2,
            int M, int N, int K, int ldc,
            const float* __restrict__ rawq, const float* __restrict__ resid)
{
  __shared__ short As[2][64*64];
  __shared__ short Bs[2][64*64];
  const int tid = threadIdx.x, wid = tid >> 6, lane = tid & 63;
  const int wr = wid >> 1, wc = wid & 1;
  const int fr = lane & 15, fq = lane >> 4;
  const int bm = blockIdx.x, bn = blockIdx.y;
  const int lrow = lane >> 3;
  const int schk = ((lane & 7) ^ lrow) * 8;
  const int nk = K >> 6;

  f32x4 acc[2][2] = {};

  auto stg = [&](int kt, int bsel) {
    const int k0 = kt << 6;
    #pragma unroll
    for (int i = 0; i < 2; ++i) {
      const int rr = wid*16 + i*8 + lrow;
      load_lds16(A + (long)(bm*64 + rr)*K + k0 + schk, &As[bsel][(wid*16 + i*8)*64]);
      load_lds16(B + (long)(bn*64 + rr)*K + k0 + schk, &Bs[bsel][(wid*16 + i*8)*64]);
    }
  };

  stg(0, 0);
  for (int t = 0; t < nk; ++t) {
    const int cur = t & 1;
    if (t + 1 < nk) {
      stg(t + 1, cur ^ 1);
      asm volatile("s_waitcnt vmcnt(4)" ::: "memory");
    } else {
      asm volatile("s_waitcnt vmcnt(0)" ::: "memory");
    }
    __builtin_amdgcn_s_barrier();
    __builtin_amdgcn_sched_barrier(0);
    #pragma unroll
    for (int kk = 0; kk < 64; kk += 32) {
      bf16x8 af[2], bv[2];
      #pragma unroll
      for (int mi = 0; mi < 2; ++mi)
        af[mi] = *(const bf16x8*)&As[cur][(wr*32 + mi*16 + fr)*64 + (((kk>>3)+fq) ^ (fr&7))*8];
      #pragma unroll
      for (int ni = 0; ni < 2; ++ni)
        bv[ni] = *(const bf16x8*)&Bs[cur][(wc*32 + ni*16 + fr)*64 + (((kk>>3)+fq) ^ (fr&7))*8];
      #pragma unroll
      for (int mi = 0; mi < 2; ++mi)
        #pragma unroll
        for (int ni = 0; ni < 2; ++ni)
          acc[mi][ni] = MFMA(af[mi], bv[ni], acc[mi][ni]);
    }
    __builtin_amdgcn_s_barrier();
  }

  #pragma unroll
  for (int mi = 0; mi < 2; ++mi) {
    #pragma unroll
    for (int r = 0; r < 4; ++r) {
      const int grow = bm*64 + wr*32 + mi*16 + fq*4 + r;
      #pragma unroll
      for (int ni = 0; ni < 2; ++ni) {
        const int gcol = bn*64 + wc*32 + ni*16 + fr;
        float v = acc[mi][ni][r];
        if (EPI == 4) v += (gcol < 96) ? bias[gcol] : bias2[gcol-96];
        else v += bias[gcol];
        const long off = (long)grow*ldc + gcol;
        if (EPI == 0) {
          if (Cf) Cf[off] = v;
          if (Cb) Cb[off] = f2bf(v);
        } else if (EPI == 1) {
          Cb[off] = f2bf(fmaxf(v, 0.0f));
        } else if (EPI == 2) {
          const float qp = v * rawq[off];
          Cf[off] = qp;
          Cb[off] = f2bf(resid[off] + qp);
        } else if (EPI == 3) {
          if (grow < MROW) { if (gcol < 512) Cb[(long)grow*512 + gcol] = f2bf(v); }
          else             { if (gcol >= 512) Cb2[(long)(grow-MROW)*256 + gcol-512] = f2bf(v); }
        } else if (EPI == 4) {
          Cf[off] = v;
        }
      }
    }
  }
}

// ---------------- out = tgt (f32 + bf16 copies) ----------------
__global__ __launch_bounds__(256)
void ew0_kernel(const float* __restrict__ tgt, float* __restrict__ out, short* __restrict__ outbf)
{
  const long i = (long)blockIdx.x*256 + threadIdx.x;
  const float4 v = ((const float4*)tgt)[i];
  ((float4*)out)[i] = v;
  ((short4*)outbf)[i] = make_short4(f2bf(v.x), f2bf(v.y), f2bf(v.z), f2bf(v.w));
}

// ---------------- ref / ref_in / sine embedding ----------------
__global__ __launch_bounds__(256)
void init_ref_kernel(const float* __restrict__ seg, const float* __restrict__ dur,
                     const float* __restrict__ valid,
                     short* __restrict__ sinebf, float* __restrict__ refin)
{
  const int m = blockIdx.x;
  const int n = m / LQN;
  const int t = threadIdx.x;
  const float c = seg[(long)m*2 + 0];
  const float w = __expf(seg[(long)m*2 + 1]);
  const float e = (float)(t & ~1) * (1.0f/256.0f);
  const float invdim = __expf(-e * 9.2103403719761836f);
  const float twopi = 6.2831853071795864f;
  const float a0 = c * twopi * invdim;
  const float a1 = w * twopi * invdim;
  const float v0 = (t & 1) ? cosf(a0) : sinf(a0);
  const float v1 = (t & 1) ? cosf(a1) : sinf(a1);
  sinebf[(long)m*512 + t]       = f2bf(v0);
  sinebf[(long)m*512 + 256 + t] = f2bf(v1);
  if (t < 6) {
    const int l = t >> 1, cc = t & 1;
    const float rv = cc ? w : c;
    refin[(long)m*6 + l*2 + cc] = rv / dur[n] * valid[n*NLV + l];
  }
}

// ---------------- MFMA attention ----------------
#define KPAD 320
#define KSTR 40
#define VSTR 328
#define PSTR 328

__global__ __launch_bounds__(256)
void attn_mfma(const short* __restrict__ qk, const short* __restrict__ vv,
               short* __restrict__ outb)
{
  __shared__ short Kl[KPAD*KSTR];
  __shared__ short Vt[DH*VSTR];
  __shared__ short Pl[4][16*PSTR];
  const int b = blockIdx.x;
  const int half = b & 1, h = (b >> 1) & 7, n = b >> 4;
  const int tid = threadIdx.x, wid = tid >> 6, lane = tid & 63;
  const int fr = lane & 15, fq = lane >> 4;

  const short* qkn = qk + (long)n*LQN*512;
  const short* vn  = vv + (long)n*LQN*256;

  for (int t = tid; t < KPAD*4; t += 256) {
    const int r = t >> 2, c = t & 3;
    bf16x8 kv = {}, vw = {};
    if (r < LQN) {
      kv = *(const bf16x8*)(qkn + (long)r*512 + 256 + h*32 + c*8);
      vw = *(const bf16x8*)(vn  + (long)r*256 + h*32 + c*8);
    }
    *(bf16x8*)&Kl[r*KSTR + c*8] = kv;
    #pragma unroll
    for (int j = 0; j < 8; ++j) Vt[(c*8+j)*VSTR + r] = vw[j];
  }
  for (int t = tid; t < 4*16*24; t += 256) {
    const int w = t / (16*24), rr = (t / 24) & 15, cc = t % 24;
    Pl[w][rr*PSTR + 304 + cc] = 0;
  }
  __syncthreads();

  const int tlo = half ? 10 : 0, thi = half ? 19 : 10;
  const float scl2 = 0.17677669529663687f * 1.4426950408889634f;

  for (int qt = tlo + wid; qt < thi; qt += 4) {
    const int q0 = qt * 16;
    const int qrow = min(q0 + fr, LQN-1);
    const bf16x8 qf = *(const bf16x8*)(qkn + (long)qrow*512 + h*32 + fq*8);
    f32x4 s[19];
    #pragma unroll
    for (int t = 0; t < 19; ++t) {
      const bf16x8 kf = *(const bf16x8*)&Kl[(t*16+fr)*KSTR + fq*8];
      s[t] = MFMA(qf, kf, ((f32x4){0.f,0.f,0.f,0.f}));
    }
    float mx[4] = {-3e38f,-3e38f,-3e38f,-3e38f};
    #pragma unroll
    for (int t = 0; t < 19; ++t) {
      const bool valid = (t < 18) || (fr < 12);
      #pragma unroll
      for (int r = 0; r < 4; ++r) if (valid) mx[r] = fmaxf(mx[r], s[t][r]);
    }
    #pragma unroll
    for (int r = 0; r < 4; ++r) {
      #pragma unroll
      for (int o = 1; o < 16; o <<= 1) mx[r] = fmaxf(mx[r], __shfl_xor(mx[r], o));
      mx[r] *= scl2;
    }
    float l[4] = {0.f,0.f,0.f,0.f};
    #pragma unroll
    for (int t = 0; t < 19; ++t) {
      const bool valid = (t < 18) || (fr < 12);
      #pragma unroll
      for (int r = 0; r < 4; ++r) {
        const float p = valid ? exp2f(s[t][r]*scl2 - mx[r]) : 0.0f;
        l[r] += p;
        Pl[wid][(fq*4+r)*PSTR + t*16 + fr] = f2bf(p);
      }
    }
    #pragma unroll
    for (int r = 0; r < 4; ++r) {
      #pragma unroll
      for (int o = 1; o < 16; o <<= 1) l[r] += __shfl_xor(l[r], o);
    }
    f32x4 o0 = {}, o1 = {};
    #pragma unroll
    for (int ck = 0; ck < 10; ++ck) {
      const bf16x8 pf = *(const bf16x8*)&Pl[wid][fr*PSTR + ck*32 + fq*8];
      const bf16x8 v0 = *(const bf16x8*)&Vt[fr*VSTR + ck*32 + fq*8];
      const bf16x8 v1 = *(const bf16x8*)&Vt[(16+fr)*VSTR + ck*32 + fq*8];
      o0 = MFMA(pf, v0, o0);
      o1 = MFMA(pf, v1, o1);
    }
    #pragma unroll
    for (int r = 0; r < 4; ++r) {
      const int qq = q0 + fq*4 + r;
      if (qq < LQN) {
        const float inv = 1.0f / l[r];
        outb[((long)(n*LQN+qq))*256 + h*32 + fr]      = f2bf(o0[r]*inv);
        outb[((long)(n*LQN+qq))*256 + h*32 + 16 + fr] = f2bf(o1[r]*inv);
      }
    }
  }
}

// ---------------- residual + LayerNorm (+ optional caq = y+qpos) ----------------
__global__ __launch_bounds__(256)
void ln_kernel(const float* __restrict__ resid, const float* __restrict__ delta,
               const float* __restrict__ g, const float* __restrict__ b,
               float* __restrict__ of, short* __restrict__ ob,
               const float* __restrict__ qpos, short* __restrict__ caqb)
{
  const int m = blockIdx.x, c = threadIdx.x;
  const long idx = (long)m*DM + c;
  const float x = resid[idx] + delta[idx];
  float s = x, s2 = x*x;
  #pragma unroll
  for (int o = 1; o < 64; o <<= 1) { s += __shfl_xor(s, o); s2 += __shfl_xor(s2, o); }
  __shared__ float rs[4], rs2[4];
  const int w = c >> 6;
  if ((c & 63) == 0) { rs[w] = s; rs2[w] = s2; }
  __syncthreads();
  s  = rs[0]+rs[1]+rs[2]+rs[3];
  s2 = rs2[0]+rs2[1]+rs2[2]+rs2[3];
  const float mean = s * (1.0f/DM);
  const float var  = s2 * (1.0f/DM) - mean*mean;
  const float y = (x - mean) * rsqrtf(var + 1e-5f) * g[c] + b[c];
  of[idx] = y;
  if (ob) ob[idx] = f2bf(y);
  if (qpos) caqb[idx] = f2bf(y + qpos[idx]);
}

// ---------------- sampling: fused prep (softmax+bilinear) + gather-MAC ----------------
__global__ __launch_bounds__(256)
void sample_kernel(const short* __restrict__ val, int ldv,
                   const float* __restrict__ offaw, const float* __restrict__ refin,
                   const int* __restrict__ tlens, const int* __restrict__ lstart,
                   short* __restrict__ cab)
{
  const int m = blockIdx.x;
  const int n = m / LQN;
  const int tid = threadIdx.x;
  __shared__ int2  lI[96];
  __shared__ float2 lW[96];
  if ((tid & 31) == 0) {
    const int h = tid >> 5;
    const float* row = offaw + (long)m*192;
    float aw[12];
    float mx = -1e30f;
    #pragma unroll
    for (int lp = 0; lp < 12; ++lp) { aw[lp] = row[96 + h*12 + lp]; mx = fmaxf(mx, aw[lp]); }
    float sum = 0.0f;
    #pragma unroll
    for (int lp = 0; lp < 12; ++lp) { aw[lp] = __expf(aw[lp]-mx); sum += aw[lp]; }
    const float invs = 1.0f / sum;
    #pragma unroll
    for (int lp = 0; lp < 12; ++lp) {
      const int l = lp >> 2;
      const int tli = tlens[l];
      const float off = row[h*12 + lp];
      const float loc = refin[(long)m*6 + l*2] + off * 0.25f * refin[(long)m*6 + l*2 + 1] * 0.5f;
      const float x = loc * (float)tli - 0.5f;
      const float x0f = floorf(x);
      const float f = x - x0f;
      const int x0 = (int)x0f;
      const int i0 = lstart[l] + min(max(x0,   0), tli-1);
      const int i1 = lstart[l] + min(max(x0+1, 0), tli-1);
      const float wgt = aw[lp]*invs;
      const float w0 = (x0   >= 0 && x0   < tli) ? wgt*(1.0f-f) : 0.0f;
      const float w1 = (x0+1 >= 0 && x0+1 < tli) ? wgt*f        : 0.0f;
      lI[h*12 + lp] = make_int2(i0, i1);
      lW[h*12 + lp] = make_float2(w0, w1);
    }
  }
  __syncthreads();
  const int h = tid >> 5;
  const short* vb = val + (long)n*TT*ldv;
  float acc = 0.0f;
  #pragma unroll
  for (int lp = 0; lp < 12; ++lp) {
    const int e = h*12 + lp;
    const int2 ii = lI[e];
    const float2 ww = lW[e];
    acc += ww.x * bf2f(vb[(long)ii.x*ldv + tid]) + ww.y * bf2f(vb[(long)ii.y*ldv + tid]);
  }
  cab[(long)m*DM + tid] = f2bf(acc);
}

// ---------------- host side ----------------
static inline void g64(hipStream_t st, int epi, const short* A, const short* B,
                       const float* bias, const float* bias2,
                       float* Cf, short* Cb, short* Cb2,
                       int M, int N, int K, int ldc,
                       const float* rawq = nullptr, const float* resid = nullptr)
{
  dim3 g(M/64, N/64), blk(256);
  switch (epi) {
    case 0: gemm64<0><<<g,blk,0,st>>>(A,B,bias,bias2,Cf,Cb,Cb2,M,N,K,ldc,rawq,resid); break;
    case 1: gemm64<1><<<g,blk,0,st>>>(A,B,bias,bias2,Cf,Cb,Cb2,M,N,K,ldc,rawq,resid); break;
    case 2: gemm64<2><<<g,blk,0,st>>>(A,B,bias,bias2,Cf,Cb,Cb2,M,N,K,ldc,rawq,resid); break;
    case 3: gemm64<3><<<g,blk,0,st>>>(A,B,bias,bias2,Cf,Cb,Cb2,M,N,K,ldc,rawq,resid); break;
    default:gemm64<4><<<g,blk,0,st>>>(A,B,bias,bias2,Cf,Cb,Cb2,M,N,K,ldc,rawq,resid); break;
  }
}

extern "C" void kernel_launch(void* const* d_in, const int* in_sizes, int n_in,
                              void* d_out, int out_size, void* d_ws, size_t ws_size,
                              hipStream_t stream)
{
  const float* tgt    = (const float*)d_in[0];
  const float* seg    = (const float*)d_in[1];
  const float* dur    = (const float*)d_in[2];
  const float* src    = (const float*)d_in[3];
  const int*   tlens  = (const int*)d_in[4];
  const int*   lstart = (const int*)d_in[5];
  const float* valid  = (const float*)d_in[6];
  const unsigned char* pmask = (const unsigned char*)d_in[7];
  const float* grid_w0 = (const float*)d_in[8];
  const float* grid_b0 = (const float*)d_in[9];
  const float* grid_w1 = (const float*)d_in[10];
  const float* grid_b1 = (const float*)d_in[11];
  const float* qs_w0 = (const float*)d_in[12];
  const float* qs_b0 = (const float*)d_in[13];
  const float* qs_w1 = (const float*)d_in[14];
  const float* qs_b1 = (const float*)d_in[15];
  const float* sa_in_w  = (const float*)d_in[16];
  const float* sa_in_b  = (const float*)d_in[17];
  const float* sa_out_w = (const float*)d_in[18];
  const float* sa_out_b = (const float*)d_in[19];
  const float* n1_g = (const float*)d_in[20];
  const float* n1_b = (const float*)d_in[21];
  const float* n2_g = (const float*)d_in[22];
  const float* n2_b = (const float*)d_in[23];
  const float* n3_g = (const float*)d_in[24];
  const float* n3_b = (const float*)d_in[25];
  const float* off_w = (const float*)d_in[26];
  const float* off_b = (const float*)d_in[27];
  const float* aw_w  = (const float*)d_in[28];
  const float* aw_b  = (const float*)d_in[29];
  const float* val_w = (const float*)d_in[30];
  const float* val_b = (const float*)d_in[31];
  const float* outp_w = (const float*)d_in[32];
  const float* outp_b = (const float*)d_in[33];
  const float* ffn_w1 = (const float*)d_in[34];
  const float* ffn_b1 = (const float*)d_in[35];
  const float* ffn_w2 = (const float*)d_in[36];
  const float* ffn_b2 = (const float*)d_in[37];

  // bf16 weight region offsets (shorts)
  const long W_G0=0, W_G1=131072, W_QS0=196608, W_QS1=262144, W_SAIN=327680,
             W_SAOUT=1507328, W_OFFAW=1900544, W_VAL=2195456,
             W_OUTP=2588672, W_FFN1=2981888, W_FFN2=4554752;

  char* ws = (char*)d_ws;
  short* wbf    = (short*)(ws + 0);
  short* sinebf = (short*)(ws + 70975488);
  short* ghbf   = (short*)(ws + 75890688);
  float* rawq   = (float*)(ws + 78348288);
  float* out    = (float*)(ws + 83263488);
  short* qcat   = (short*)(ws + 88178688);    // [9600][256]: rows 0..4799 = qbf, 4800.. = outbf
  short* qbf    = qcat;
  short* outbf  = qcat + (long)MROW*DM;
  short* t1bf   = (short*)(ws + 93093888);
  float* qpos   = (float*)(ws + 95551488);
  short* qkbf   = (short*)(ws + 100466688);   // [4800][512]
  short* vbf    = (short*)(ws + 105381888);   // [4800][256]
  short* attnbf = (short*)(ws + 107839488);
  float* tmpf   = (float*)(ws + 110297088);
  short* caqb   = (short*)(ws + 115212288);
  float* offaw  = (float*)(ws + 117669888);   // [4800][192]
  short* cabf   = (short*)(ws + 128729088);
  short* ffnhbf = (short*)(ws + 131186688);
  float* refin  = (float*)(ws + 141017088);
  short* valbf  = (short*)(ws + 141132288);   // [114688][256]

  CvtPtrs cp;
  cp.p[0]=grid_w0; cp.p[1]=grid_w1; cp.p[2]=qs_w0; cp.p[3]=qs_w1; cp.p[4]=sa_in_w;
  cp.p[5]=sa_out_w; cp.p[6]=off_w; cp.p[7]=aw_w; cp.p[8]=val_w; cp.p[9]=outp_w;
  cp.p[10]=ffn_w1; cp.p[11]=ffn_w2;
  cvt_all_kernel<<<dim3(5984), dim3(256), 0, stream>>>(cp, wbf);

  ew0_kernel<<<dim3(1200), dim3(256), 0, stream>>>(tgt, out, outbf);
  init_ref_kernel<<<dim3(MROW), dim3(256), 0, stream>>>(seg, dur, valid, sinebf, refin);

  g64(stream, 1, sinebf, wbf + W_G0, grid_b0, nullptr, nullptr, ghbf, nullptr, MROW, 256, 512, 256);
  g64(stream, 0, ghbf,   wbf + W_G1, grid_b1, nullptr, rawq, nullptr, nullptr, MROW, 256, 256, 256);

  for (int l = 0; l < NLAY; ++l) {
    g64(stream, 1, outbf, wbf + W_QS0, qs_b0, nullptr, nullptr, t1bf, nullptr, MROW, 256, 256, 256);
    g64(stream, 2, t1bf,  wbf + W_QS1, qs_b1, nullptr, qpos, qbf, nullptr, MROW, 256, 256, 256,
        rawq, out);
    g64(stream, 3, qcat, wbf + W_SAIN + (long)l*196608, sa_in_b + l*768, nullptr,
        nullptr, qkbf, vbf, 2*MROW, 768, 256, 0);
    attn_mfma<<<dim3(256), dim3(256), 0, stream>>>(qkbf, vbf, attnbf);
    g64(stream, 0, attnbf, wbf + W_SAOUT + (long)l*65536, sa_out_b + l*256, nullptr,
        tmpf, nullptr, nullptr, MROW, 256, 256, 256);
    ln_kernel<<<dim3(MROW), dim3(256), 0, stream>>>(out, tmpf, n1_g + l*256, n1_b + l*256,
                                                    out, outbf, qpos, caqb);
    g64(stream, 4, caqb, wbf + W_OFFAW + (long)l*49152, off_b + l*96, aw_b + l*96,
        offaw, nullptr, nullptr, MROW, 192, 256, 192);
    val_gemm<<<dim3(896), dim3(512), 0, stream>>>(
        src, wbf + W_VAL + (long)l*65536, val_b + l*256, valbf, pmask);
    sample_kernel<<<dim3(MROW), dim3(256), 0, stream>>>(
        valbf, 256, offaw, refin, tlens, lstart, cabf);
    g64(stream, 0, cabf, wbf + W_OUTP + (long)l*65536, outp_b + l*256, nullptr,
        tmpf, nullptr, nullptr, MROW, 256, 256, 256);
    ln_kernel<<<dim3(MROW), dim3(256), 0, stream>>>(out, tmpf, n2_g + l*256, n2_b + l*256,
                                                    out, outbf, nullptr, nullptr);
    g64(stream, 1, outbf, wbf + W_FFN1 + (long)l*262144, ffn_b1 + l*1024, nullptr,
        nullptr, ffnhbf, nullptr, MROW, 1024, 256, 1024);
    g64(stream, 0, ffnhbf, wbf + W_FFN2 + (long)l*262144, ffn_b2 + l*256, nullptr,
        tmpf, nullptr, nullptr, MROW, 256, 1024, 256);
    float* of = (l == NLAY-1) ? (float*)d_out : out;
    ln_kernel<<<dim3(MROW), dim3(256), 0, stream>>>(out, tmpf, n3_g + l*256, n3_b + l*256,
                                                    of, outbf, nullptr, nullptr);
  }
}

// Round 7
// 1039.339 us; speedup vs baseline: 2.5715x; 1.0121x over previous
//
#include <hip/hip_runtime.h>
#include <cstdint>

#define NB   16
#define LQN  300
#define DM   256
#define NH   8
#define DH   32
#define NLV  3
#define DFFN 1024
#define NLAY 6
#define TT   7168
#define MROW (NB*LQN)   // 4800
#define SROW (NB*TT)    // 114688

typedef __attribute__((ext_vector_type(8))) short bf16x8;
typedef __attribute__((ext_vector_type(4))) float f32x4;

__device__ __forceinline__ float bf2f(short u) {
  unsigned x = ((unsigned)(unsigned short)u) << 16;
  return __builtin_bit_cast(float, x);
}
__device__ __forceinline__ short f2bf(float f) {
  unsigned u = __builtin_bit_cast(unsigned, f);
  u += 0x7fffu + ((u >> 16) & 1u);   // RNE
  return (short)(u >> 16);
}
__device__ __forceinline__ void load_lds16(const void* g, void* l) {
  __builtin_amdgcn_global_load_lds(
      (const __attribute__((address_space(1))) unsigned int*)g,
      (__attribute__((address_space(3))) unsigned int*)l, 16, 0, 0);
}
#define MFMA(a,b,c) __builtin_amdgcn_mfma_f32_16x16x32_bf16((a),(b),(c),0,0,0)

// ---------------- weight + src fp32->bf16 conversion ----------------
struct CvtPtrs { const float* p[13]; };

__global__ __launch_bounds__(256)
void cvt_all_kernel(CvtPtrs ptrs, short* __restrict__ dst)
{
  const long gid = (long)blockIdx.x*256 + threadIdx.x;  // float4 units
  const long cums[14] = {0,32768,49152,65536,81920,376832,475136,512000,
                         548864,647168,745472,1138688,1531904,8871936};
  int s = 0;
  #pragma unroll
  for (int i = 1; i < 13; ++i) s += (gid >= cums[i]) ? 1 : 0;
  const long rel = gid - cums[s];
  const float4 v = ((const float4*)ptrs.p[s])[rel];
  long dstIdx = gid;
  if (s == 6) { const long l = rel/6144, w = rel%6144; dstIdx = 475136 + l*12288 + w; }
  else if (s == 7) { const long l = rel/6144, w = rel%6144; dstIdx = 475136 + l*12288 + 6144 + w; }
  ((short4*)dst)[dstIdx] = make_short4(f2bf(v.x), f2bf(v.y), f2bf(v.z), f2bf(v.w));
}

// ---------------- val projection: barrier-free streaming GEMM (H=2, bf16 A) ----------------
// valbf[r][c] = bf16((sum_k srcbf[r][k]*vw[c][k] + vb[c]) * mask(r)); B fully in padded LDS.
#define VLS 264   // padded LDS row stride (shorts)

__global__ __launch_bounds__(512, 1)
void val_gemm(const short* __restrict__ srcbf, const short* __restrict__ Bw,
              const float* __restrict__ bias, short* __restrict__ Cb,
              const unsigned char* __restrict__ rowmask)
{
  __shared__ short Bs[256*VLS];   // 135,168 B
  const int tid = threadIdx.x, wid = tid >> 6, lane = tid & 63;
  const int fr = lane & 15, fq = lane >> 4;

  // stage B [256][256] bf16 via plain ds_write (padded stride) — proven R6 pattern
  for (int t = tid; t < 8192; t += 512) {
    const int row = t >> 5, ch = t & 31;
    const bf16x8 v = *(const bf16x8*)(Bw + row*256 + ch*8);
    *(bf16x8*)&Bs[row*VLS + ch*8] = v;
  }
  __syncthreads();

  // one 32-row strip per wave: grid.x*8 waves == SROW/32 strips exactly (448*8=3584)
  const int rbase = (blockIdx.x*8 + wid) * 32;

  // load ALL A for the strip upfront (16 × 16B/lane in flight)
  bf16x8 a[2][8];
  #pragma unroll
  for (int h = 0; h < 2; ++h)
    #pragma unroll
    for (int ks = 0; ks < 8; ++ks)
      a[h][ks] = *(const bf16x8*)(srcbf + (long)(rbase + h*16 + fr)*256 + ks*32 + fq*8);

  f32x4 acc[2][16] = {};
  #pragma unroll
  for (int ks = 0; ks < 8; ++ks) {
    #pragma unroll
    for (int nt = 0; nt < 16; ++nt) {
      const bf16x8 b = *(const bf16x8*)&Bs[(nt*16 + fr)*VLS + ks*32 + fq*8];
      acc[0][nt] = MFMA(a[0][ks], b, acc[0][nt]);
      acc[1][nt] = MFMA(a[1][ks], b, acc[1][nt]);
    }
  }

  #pragma unroll
  for (int h = 0; h < 2; ++h) {
    #pragma unroll
    for (int r = 0; r < 4; ++r) {
      const int grow = rbase + h*16 + fq*4 + r;
      const float msc = rowmask[grow] ? 0.0f : 1.0f;
      #pragma unroll
      for (int nt = 0; nt < 16; ++nt) {
        const int gcol = nt*16 + fr;
        Cb[(long)grow*256 + gcol] = f2bf((acc[h][nt][r] + bias[gcol]) * msc);
      }
    }
  }
}

// ---------------- GEMM 64x64 tile, A[M,K] @ B[N,K]^T + bias (R3-proven) ----------------
// EPI: 0 plain, 1 relu->Cb, 2 qpos, 3 sain-route, 4 two-bias->Cf
template<int EPI>
__global__ __launch_bounds__(256)
void gemm64(const short* __restrict__ A, const short* __restrict__ B,
            const float* __restrict__ bias, const float* __restrict__ bias2,
            float* __restrict__ Cf, short* __restrict__ Cb, short* __restrict__ Cb2,
            int M, int N, int K, int ldc,
            const float* __restrict__ rawq, const float* __restrict__ resid)
{
  __shared__ short As[2][64*64];
  __shared__ short Bs[2][64*64];
  const int tid = threadIdx.x, wid = tid >> 6, lane = tid & 63;
  const int wr = wid >> 1, wc = wid & 1;
  const int fr = lane & 15, fq = lane >> 4;
  const int bm = blockIdx.x, bn = blockIdx.y;
  const int lrow = lane >> 3;
  const int schk = ((lane & 7) ^ lrow) * 8;
  const int nk = K >> 6;

  f32x4 acc[2][2] = {};

  auto stg = [&](int kt, int bsel) {
    const int k0 = kt << 6;
    #pragma unroll
    for (int i = 0; i < 2; ++i) {
      const int rr = wid*16 + i*8 + lrow;
      load_lds16(A + (long)(bm*64 + rr)*K + k0 + schk, &As[bsel][(wid*16 + i*8)*64]);
      load_lds16(B + (long)(bn*64 + rr)*K + k0 + schk, &Bs[bsel][(wid*16 + i*8)*64]);
    }
  };

  stg(0, 0);
  for (int t = 0; t < nk; ++t) {
    const int cur = t & 1;
    if (t + 1 < nk) {
      stg(t + 1, cur ^ 1);
      asm volatile("s_waitcnt vmcnt(4)" ::: "memory");
    } else {
      asm volatile("s_waitcnt vmcnt(0)" ::: "memory");
    }
    __builtin_amdgcn_s_barrier();
    __builtin_amdgcn_sched_barrier(0);
    #pragma unroll
    for (int kk = 0; kk < 64; kk += 32) {
      bf16x8 af[2], bv[2];
      #pragma unroll
      for (int mi = 0; mi < 2; ++mi)
        af[mi] = *(const bf16x8*)&As[cur][(wr*32 + mi*16 + fr)*64 + (((kk>>3)+fq) ^ (fr&7))*8];
      #pragma unroll
      for (int ni = 0; ni < 2; ++ni)
        bv[ni] = *(const bf16x8*)&Bs[cur][(wc*32 + ni*16 + fr)*64 + (((kk>>3)+fq) ^ (fr&7))*8];
      #pragma unroll
      for (int mi = 0; mi < 2; ++mi)
        #pragma unroll
        for (int ni = 0; ni < 2; ++ni)
          acc[mi][ni] = MFMA(af[mi], bv[ni], acc[mi][ni]);
    }
    __builtin_amdgcn_s_barrier();
  }

  #pragma unroll
  for (int mi = 0; mi < 2; ++mi) {
    #pragma unroll
    for (int r = 0; r < 4; ++r) {
      const int grow = bm*64 + wr*32 + mi*16 + fq*4 + r;
      #pragma unroll
      for (int ni = 0; ni < 2; ++ni) {
        const int gcol = bn*64 + wc*32 + ni*16 + fr;
        float v = acc[mi][ni][r];
        if (EPI == 4) v += (gcol < 96) ? bias[gcol] : bias2[gcol-96];
        else v += bias[gcol];
        const long off = (long)grow*ldc + gcol;
        if (EPI == 0) {
          if (Cf) Cf[off] = v;
          if (Cb) Cb[off] = f2bf(v);
        } else if (EPI == 1) {
          Cb[off] = f2bf(fmaxf(v, 0.0f));
        } else if (EPI == 2) {
          const float qp = v * rawq[off];
          Cf[off] = qp;
          Cb[off] = f2bf(resid[off] + qp);
        } else if (EPI == 3) {
          if (grow < MROW) { if (gcol < 512) Cb[(long)grow*512 + gcol] = f2bf(v); }
          else             { if (gcol >= 512) Cb2[(long)(grow-MROW)*256 + gcol-512] = f2bf(v); }
        } else if (EPI == 4) {
          Cf[off] = v;
        }
      }
    }
  }
}

// ---------------- out = tgt (f32 + bf16 copies) ----------------
__global__ __launch_bounds__(256)
void ew0_kernel(const float* __restrict__ tgt, float* __restrict__ out, short* __restrict__ outbf)
{
  const long i = (long)blockIdx.x*256 + threadIdx.x;
  const float4 v = ((const float4*)tgt)[i];
  ((float4*)out)[i] = v;
  ((short4*)outbf)[i] = make_short4(f2bf(v.x), f2bf(v.y), f2bf(v.z), f2bf(v.w));
}

// ---------------- ref / ref_in / sine embedding ----------------
__global__ __launch_bounds__(256)
void init_ref_kernel(const float* __restrict__ seg, const float* __restrict__ dur,
                     const float* __restrict__ valid,
                     short* __restrict__ sinebf, float* __restrict__ refin)
{
  const int m = blockIdx.x;
  const int n = m / LQN;
  const int t = threadIdx.x;
  const float c = seg[(long)m*2 + 0];
  const float w = __expf(seg[(long)m*2 + 1]);
  const float e = (float)(t & ~1) * (1.0f/256.0f);
  const float invdim = __expf(-e * 9.2103403719761836f);
  const float twopi = 6.2831853071795864f;
  const float a0 = c * twopi * invdim;
  const float a1 = w * twopi * invdim;
  const float v0 = (t & 1) ? cosf(a0) : sinf(a0);
  const float v1 = (t & 1) ? cosf(a1) : sinf(a1);
  sinebf[(long)m*512 + t]       = f2bf(v0);
  sinebf[(long)m*512 + 256 + t] = f2bf(v1);
  if (t < 6) {
    const int l = t >> 1, cc = t & 1;
    const float rv = cc ? w : c;
    refin[(long)m*6 + l*2 + cc] = rv / dur[n] * valid[n*NLV + l];
  }
}

// ---------------- MFMA attention ----------------
#define KPAD 320
#define KSTR 40
#define VSTR 328
#define PSTR 328

__global__ __launch_bounds__(256)
void attn_mfma(const short* __restrict__ qk, const short* __restrict__ vv,
               short* __restrict__ outb)
{
  __shared__ short Kl[KPAD*KSTR];
  __shared__ short Vt[DH*VSTR];
  __shared__ short Pl[4][16*PSTR];
  const int b = blockIdx.x;
  const int half = b & 1, h = (b >> 1) & 7, n = b >> 4;
  const int tid = threadIdx.x, wid = tid >> 6, lane = tid & 63;
  const int fr = lane & 15, fq = lane >> 4;

  const short* qkn = qk + (long)n*LQN*512;
  const short* vn  = vv + (long)n*LQN*256;

  for (int t = tid; t < KPAD*4; t += 256) {
    const int r = t >> 2, c = t & 3;
    bf16x8 kv = {}, vw = {};
    if (r < LQN) {
      kv = *(const bf16x8*)(qkn + (long)r*512 + 256 + h*32 + c*8);
      vw = *(const bf16x8*)(vn  + (long)r*256 + h*32 + c*8);
    }
    *(bf16x8*)&Kl[r*KSTR + c*8] = kv;
    #pragma unroll
    for (int j = 0; j < 8; ++j) Vt[(c*8+j)*VSTR + r] = vw[j];
  }
  for (int t = tid; t < 4*16*24; t += 256) {
    const int w = t / (16*24), rr = (t / 24) & 15, cc = t % 24;
    Pl[w][rr*PSTR + 304 + cc] = 0;
  }
  __syncthreads();

  const int tlo = half ? 10 : 0, thi = half ? 19 : 10;
  const float scl2 = 0.17677669529663687f * 1.4426950408889634f;

  for (int qt = tlo + wid; qt < thi; qt += 4) {
    const int q0 = qt * 16;
    const int qrow = min(q0 + fr, LQN-1);
    const bf16x8 qf = *(const bf16x8*)(qkn + (long)qrow*512 + h*32 + fq*8);
    f32x4 s[19];
    #pragma unroll
    for (int t = 0; t < 19; ++t) {
      const bf16x8 kf = *(const bf16x8*)&Kl[(t*16+fr)*KSTR + fq*8];
      s[t] = MFMA(qf, kf, ((f32x4){0.f,0.f,0.f,0.f}));
    }
    float mx[4] = {-3e38f,-3e38f,-3e38f,-3e38f};
    #pragma unroll
    for (int t = 0; t < 19; ++t) {
      const bool valid = (t < 18) || (fr < 12);
      #pragma unroll
      for (int r = 0; r < 4; ++r) if (valid) mx[r] = fmaxf(mx[r], s[t][r]);
    }
    #pragma unroll
    for (int r = 0; r < 4; ++r) {
      #pragma unroll
      for (int o = 1; o < 16; o <<= 1) mx[r] = fmaxf(mx[r], __shfl_xor(mx[r], o));
      mx[r] *= scl2;
    }
    float l[4] = {0.f,0.f,0.f,0.f};
    #pragma unroll
    for (int t = 0; t < 19; ++t) {
      const bool valid = (t < 18) || (fr < 12);
      #pragma unroll
      for (int r = 0; r < 4; ++r) {
        const float p = valid ? exp2f(s[t][r]*scl2 - mx[r]) : 0.0f;
        l[r] += p;
        Pl[wid][(fq*4+r)*PSTR + t*16 + fr] = f2bf(p);
      }
    }
    #pragma unroll
    for (int r = 0; r < 4; ++r) {
      #pragma unroll
      for (int o = 1; o < 16; o <<= 1) l[r] += __shfl_xor(l[r], o);
    }
    f32x4 o0 = {}, o1 = {};
    #pragma unroll
    for (int ck = 0; ck < 10; ++ck) {
      const bf16x8 pf = *(const bf16x8*)&Pl[wid][fr*PSTR + ck*32 + fq*8];
      const bf16x8 v0 = *(const bf16x8*)&Vt[fr*VSTR + ck*32 + fq*8];
      const bf16x8 v1 = *(const bf16x8*)&Vt[(16+fr)*VSTR + ck*32 + fq*8];
      o0 = MFMA(pf, v0, o0);
      o1 = MFMA(pf, v1, o1);
    }
    #pragma unroll
    for (int r = 0; r < 4; ++r) {
      const int qq = q0 + fq*4 + r;
      if (qq < LQN) {
        const float inv = 1.0f / l[r];
        outb[((long)(n*LQN+qq))*256 + h*32 + fr]      = f2bf(o0[r]*inv);
        outb[((long)(n*LQN+qq))*256 + h*32 + 16 + fr] = f2bf(o1[r]*inv);
      }
    }
  }
}

// ---------------- residual + LayerNorm (+ optional caq = y+qpos) ----------------
__global__ __launch_bounds__(256)
void ln_kernel(const float* __restrict__ resid, const float* __restrict__ delta,
               const float* __restrict__ g, const float* __restrict__ b,
               float* __restrict__ of, short* __restrict__ ob,
               const float* __restrict__ qpos, short* __restrict__ caqb)
{
  const int m = blockIdx.x, c = threadIdx.x;
  const long idx = (long)m*DM + c;
  const float x = resid[idx] + delta[idx];
  float s = x, s2 = x*x;
  #pragma unroll
  for (int o = 1; o < 64; o <<= 1) { s += __shfl_xor(s, o); s2 += __shfl_xor(s2, o); }
  __shared__ float rs[4], rs2[4];
  const int w = c >> 6;
  if ((c & 63) == 0) { rs[w] = s; rs2[w] = s2; }
  __syncthreads();
  s  = rs[0]+rs[1]+rs[2]+rs[3];
  s2 = rs2[0]+rs2[1]+rs2[2]+rs2[3];
  const float mean = s * (1.0f/DM);
  const float var  = s2 * (1.0f/DM) - mean*mean;
  const float y = (x - mean) * rsqrtf(var + 1e-5f) * g[c] + b[c];
  of[idx] = y;
  if (ob) ob[idx] = f2bf(y);
  if (qpos) caqb[idx] = f2bf(y + qpos[idx]);
}

// ---------------- sampling: fused prep (softmax+bilinear) + gather-MAC ----------------
__global__ __launch_bounds__(256)
void sample_kernel(const short* __restrict__ val, int ldv,
                   const float* __restrict__ offaw, const float* __restrict__ refin,
                   const int* __restrict__ tlens, const int* __restrict__ lstart,
                   short* __restrict__ cab)
{
  const int m = blockIdx.x;
  const int n = m / LQN;
  const int tid = threadIdx.x;
  __shared__ int2  lI[96];
  __shared__ float2 lW[96];
  if ((tid & 31) == 0) {
    const int h = tid >> 5;
    const float* row = offaw + (long)m*192;
    float aw[12];
    float mx = -1e30f;
    #pragma unroll
    for (int lp = 0; lp < 12; ++lp) { aw[lp] = row[96 + h*12 + lp]; mx = fmaxf(mx, aw[lp]); }
    float sum = 0.0f;
    #pragma unroll
    for (int lp = 0; lp < 12; ++lp) { aw[lp] = __expf(aw[lp]-mx); sum += aw[lp]; }
    const float invs = 1.0f / sum;
    #pragma unroll
    for (int lp = 0; lp < 12; ++lp) {
      const int l = lp >> 2;
      const int tli = tlens[l];
      const float off = row[h*12 + lp];
      const float loc = refin[(long)m*6 + l*2] + off * 0.25f * refin[(long)m*6 + l*2 + 1] * 0.5f;
      const float x = loc * (float)tli - 0.5f;
      const float x0f = floorf(x);
      const float f = x - x0f;
      const int x0 = (int)x0f;
      const int i0 = lstart[l] + min(max(x0,   0), tli-1);
      const int i1 = lstart[l] + min(max(x0+1, 0), tli-1);
      const float wgt = aw[lp]*invs;
      const float w0 = (x0   >= 0 && x0   < tli) ? wgt*(1.0f-f) : 0.0f;
      const float w1 = (x0+1 >= 0 && x0+1 < tli) ? wgt*f        : 0.0f;
      lI[h*12 + lp] = make_int2(i0, i1);
      lW[h*12 + lp] = make_float2(w0, w1);
    }
  }
  __syncthreads();
  const int h = tid >> 5;
  const short* vb = val + (long)n*TT*ldv;
  float acc = 0.0f;
  #pragma unroll
  for (int lp = 0; lp < 12; ++lp) {
    const int e = h*12 + lp;
    const int2 ii = lI[e];
    const float2 ww = lW[e];
    acc += ww.x * bf2f(vb[(long)ii.x*ldv + tid]) + ww.y * bf2f(vb[(long)ii.y*ldv + tid]);
  }
  cab[(long)m*DM + tid] = f2bf(acc);
}

// ---------------- host side ----------------
static inline void g64(hipStream_t st, int epi, const short* A, const short* B,
                       const float* bias, const float* bias2,
                       float* Cf, short* Cb, short* Cb2,
                       int M, int N, int K, int ldc,
                       const float* rawq = nullptr, const float* resid = nullptr)
{
  dim3 g(M/64, N/64), blk(256);
  switch (epi) {
    case 0: gemm64<0><<<g,blk,0,st>>>(A,B,bias,bias2,Cf,Cb,Cb2,M,N,K,ldc,rawq,resid); break;
    case 1: gemm64<1><<<g,blk,0,st>>>(A,B,bias,bias2,Cf,Cb,Cb2,M,N,K,ldc,rawq,resid); break;
    case 2: gemm64<2><<<g,blk,0,st>>>(A,B,bias,bias2,Cf,Cb,Cb2,M,N,K,ldc,rawq,resid); break;
    case 3: gemm64<3><<<g,blk,0,st>>>(A,B,bias,bias2,Cf,Cb,Cb2,M,N,K,ldc,rawq,resid); break;
    default:gemm64<4><<<g,blk,0,st>>>(A,B,bias,bias2,Cf,Cb,Cb2,M,N,K,ldc,rawq,resid); break;
  }
}

extern "C" void kernel_launch(void* const* d_in, const int* in_sizes, int n_in,
                              void* d_out, int out_size, void* d_ws, size_t ws_size,
                              hipStream_t stream)
{
  const float* tgt    = (const float*)d_in[0];
  const float* seg    = (const float*)d_in[1];
  const float* dur    = (const float*)d_in[2];
  const float* src    = (const float*)d_in[3];
  const int*   tlens  = (const int*)d_in[4];
  const int*   lstart = (const int*)d_in[5];
  const float* valid  = (const float*)d_in[6];
  const unsigned char* pmask = (const unsigned char*)d_in[7];
  const float* grid_w0 = (const float*)d_in[8];
  const float* grid_b0 = (const float*)d_in[9];
  const float* grid_w1 = (const float*)d_in[10];
  const float* grid_b1 = (const float*)d_in[11];
  const float* qs_w0 = (const float*)d_in[12];
  const float* qs_b0 = (const float*)d_in[13];
  const float* qs_w1 = (const float*)d_in[14];
  const float* qs_b1 = (const float*)d_in[15];
  const float* sa_in_w  = (const float*)d_in[16];
  const float* sa_in_b  = (const float*)d_in[17];
  const float* sa_out_w = (const float*)d_in[18];
  const float* sa_out_b = (const float*)d_in[19];
  const float* n1_g = (const float*)d_in[20];
  const float* n1_b = (const float*)d_in[21];
  const float* n2_g = (const float*)d_in[22];
  const float* n2_b = (const float*)d_in[23];
  const float* n3_g = (const float*)d_in[24];
  const float* n3_b = (const float*)d_in[25];
  const float* off_w = (const float*)d_in[26];
  const float* off_b = (const float*)d_in[27];
  const float* aw_w  = (const float*)d_in[28];
  const float* aw_b  = (const float*)d_in[29];
  const float* val_w = (const float*)d_in[30];
  const float* val_b = (const float*)d_in[31];
  const float* outp_w = (const float*)d_in[32];
  const float* outp_b = (const float*)d_in[33];
  const float* ffn_w1 = (const float*)d_in[34];
  const float* ffn_b1 = (const float*)d_in[35];
  const float* ffn_w2 = (const float*)d_in[36];
  const float* ffn_b2 = (const float*)d_in[37];

  // bf16 weight region offsets (shorts); src bf16 follows weights EXACTLY (58,720,256 B gap)
  const long W_G0=0, W_G1=131072, W_QS0=196608, W_QS1=262144, W_SAIN=327680,
             W_SAOUT=1507328, W_OFFAW=1900544, W_VAL=2195456,
             W_OUTP=2588672, W_FFN1=2981888, W_FFN2=4554752, W_SRC=6127616;

  char* ws = (char*)d_ws;
  short* wbf    = (short*)(ws + 0);           // weights 12,255,232 B + src bf16 58,720,256 B
  short* srcbf  = wbf + W_SRC;                // = ws + 12,255,232
  short* sinebf = (short*)(ws + 70975488);
  short* ghbf   = (short*)(ws + 75890688);
  float* rawq   = (float*)(ws + 78348288);
  float* out    = (float*)(ws + 83263488);
  short* qcat   = (short*)(ws + 88178688);    // [9600][256]: rows 0..4799 = qbf, 4800.. = outbf
  short* qbf    = qcat;
  short* outbf  = qcat + (long)MROW*DM;
  short* t1bf   = (short*)(ws + 93093888);
  float* qpos   = (float*)(ws + 95551488);
  short* qkbf   = (short*)(ws + 100466688);   // [4800][512]
  short* vbf    = (short*)(ws + 105381888);   // [4800][256]
  short* attnbf = (short*)(ws + 107839488);
  float* tmpf   = (float*)(ws + 110297088);
  short* caqb   = (short*)(ws + 115212288);
  float* offaw  = (float*)(ws + 117669888);   // [4800][192]
  short* cabf   = (short*)(ws + 128729088);
  short* ffnhbf = (short*)(ws + 131186688);
  float* refin  = (float*)(ws + 141017088);
  short* valbf  = (short*)(ws + 141132288);   // [114688][256]

  CvtPtrs cp;
  cp.p[0]=grid_w0; cp.p[1]=grid_w1; cp.p[2]=qs_w0; cp.p[3]=qs_w1; cp.p[4]=sa_in_w;
  cp.p[5]=sa_out_w; cp.p[6]=off_w; cp.p[7]=aw_w; cp.p[8]=val_w; cp.p[9]=outp_w;
  cp.p[10]=ffn_w1; cp.p[11]=ffn_w2; cp.p[12]=src;
  cvt_all_kernel<<<dim3(34656), dim3(256), 0, stream>>>(cp, wbf);

  ew0_kernel<<<dim3(1200), dim3(256), 0, stream>>>(tgt, out, outbf);
  init_ref_kernel<<<dim3(MROW), dim3(256), 0, stream>>>(seg, dur, valid, sinebf, refin);

  g64(stream, 1, sinebf, wbf + W_G0, grid_b0, nullptr, nullptr, ghbf, nullptr, MROW, 256, 512, 256);
  g64(stream, 0, ghbf,   wbf + W_G1, grid_b1, nullptr, rawq, nullptr, nullptr, MROW, 256, 256, 256);

  for (int l = 0; l < NLAY; ++l) {
    g64(stream, 1, outbf, wbf + W_QS0, qs_b0, nullptr, nullptr, t1bf, nullptr, MROW, 256, 256, 256);
    g64(stream, 2, t1bf,  wbf + W_QS1, qs_b1, nullptr, qpos, qbf, nullptr, MROW, 256, 256, 256,
        rawq, out);
    g64(stream, 3, qcat, wbf + W_SAIN + (long)l*196608, sa_in_b + l*768, nullptr,
        nullptr, qkbf, vbf, 2*MROW, 768, 256, 0);
    attn_mfma<<<dim3(256), dim3(256), 0, stream>>>(qkbf, vbf, attnbf);
    g64(stream, 0, attnbf, wbf + W_SAOUT + (long)l*65536, sa_out_b + l*256, nullptr,
        tmpf, nullptr, nullptr, MROW, 256, 256, 256);
    ln_kernel<<<dim3(MROW), dim3(256), 0, stream>>>(out, tmpf, n1_g + l*256, n1_b + l*256,
                                                    out, outbf, qpos, caqb);
    g64(stream, 4, caqb, wbf + W_OFFAW + (long)l*49152, off_b + l*96, aw_b + l*96,
        offaw, nullptr, nullptr, MROW, 192, 256, 192);
    val_gemm<<<dim3(448), dim3(512), 0, stream>>>(
        srcbf, wbf + W_VAL + (long)l*65536, val_b + l*256, valbf, pmask);
    sample_kernel<<<dim3(MROW), dim3(256), 0, stream>>>(
        valbf, 256, offaw, refin, tlens, lstart, cabf);
    g64(stream, 0, cabf, wbf + W_OUTP + (long)l*65536, outp_b + l*256, nullptr,
        tmpf, nullptr, nullptr, MROW, 256, 256, 256);
    ln_kernel<<<dim3(MROW), dim3(256), 0, stream>>>(out, tmpf, n2_g + l*256, n2_b + l*256,
                                                    out, outbf, nullptr, nullptr);
    g64(stream, 1, outbf, wbf + W_FFN1 + (long)l*262144, ffn_b1 + l*1024, nullptr,
        nullptr, ffnhbf, nullptr, MROW, 1024, 256, 1024);
    g64(stream, 0, ffnhbf, wbf + W_FFN2 + (long)l*262144, ffn_b2 + l*256, nullptr,
        tmpf, nullptr, nullptr, MROW, 256, 1024, 256);
    float* of = (l == NLAY-1) ? (float*)d_out : out;
    ln_kernel<<<dim3(MROW), dim3(256), 0, stream>>>(out, tmpf, n3_g + l*256, n3_b + l*256,
                                                    of, outbf, nullptr, nullptr);
  }
}

// Round 9
// 995.884 us; speedup vs baseline: 2.6837x; 1.0436x over previous
//
#include <hip/hip_runtime.h>
#include <cstdint>

#define NB   16
#define LQN  300
#define DM   256
#define NH   8
#define DH   32
#define NLV  3
#define DFFN 1024
#define NLAY 6
#define TT   7168
#define MROW (NB*LQN)   // 4800
#define SROW (NB*TT)    // 114688

typedef __attribute__((ext_vector_type(8))) short bf16x8;
typedef __attribute__((ext_vector_type(4))) float f32x4;

__device__ __forceinline__ float bf2f(short u) {
  unsigned x = ((unsigned)(unsigned short)u) << 16;
  return __builtin_bit_cast(float, x);
}
__device__ __forceinline__ short f2bf(float f) {
  unsigned u = __builtin_bit_cast(unsigned, f);
  u += 0x7fffu + ((u >> 16) & 1u);   // RNE
  return (short)(u >> 16);
}
__device__ __forceinline__ void load_lds16(const void* g, void* l) {
  __builtin_amdgcn_global_load_lds(
      (const __attribute__((address_space(1))) unsigned int*)g,
      (__attribute__((address_space(3))) unsigned int*)l, 16, 0, 0);
}
#define MFMA(a,b,c) __builtin_amdgcn_mfma_f32_16x16x32_bf16((a),(b),(c),0,0,0)

// ---------------- weight + src fp32->bf16 conversion ----------------
struct CvtPtrs { const float* p[13]; };

__global__ __launch_bounds__(256)
void cvt_all_kernel(CvtPtrs ptrs, short* __restrict__ dst)
{
  const long gid = (long)blockIdx.x*256 + threadIdx.x;  // float4 units
  const long cums[14] = {0,32768,49152,65536,81920,376832,475136,512000,
                         548864,647168,745472,1138688,1531904,8871936};
  int s = 0;
  #pragma unroll
  for (int i = 1; i < 13; ++i) s += (gid >= cums[i]) ? 1 : 0;
  const long rel = gid - cums[s];
  const float4 v = ((const float4*)ptrs.p[s])[rel];
  long dstIdx = gid;
  if (s == 6) { const long l = rel/6144, w = rel%6144; dstIdx = 475136 + l*12288 + w; }
  else if (s == 7) { const long l = rel/6144, w = rel%6144; dstIdx = 475136 + l*12288 + 6144 + w; }
  ((short4*)dst)[dstIdx] = make_short4(f2bf(v.x), f2bf(v.y), f2bf(v.z), f2bf(v.w));
}

// ---------------- val projection: barrier-free streaming GEMM, vectorized stores ----------------
// LDS: Bs[row][ch ^ ((row>>4)&7)] = B[row][ch]; read tile nt at LDS row fr*16+nt,
// logical chunk ks*4+fq -> stored chunk (ks*4+fq)^(fr&7). Lane owns output cols fr*16..fr*16+15.
#define VLS 264   // padded LDS row stride (shorts)

__global__ __launch_bounds__(512, 1)
void val_gemm(const short* __restrict__ srcbf, const short* __restrict__ Bw,
              const float* __restrict__ bias, short* __restrict__ Cb,
              const unsigned char* __restrict__ rowmask)
{
  __shared__ short Bs[256*VLS];   // 135,168 B
  const int tid = threadIdx.x, wid = tid >> 6, lane = tid & 63;
  const int fr = lane & 15, fq = lane >> 4;

  for (int t = tid; t < 8192; t += 512) {
    const int row = t >> 5, ch = t & 31;
    const int chs = ch ^ ((row >> 4) & 7);
    *(bf16x8*)&Bs[row*VLS + chs*8] = *(const bf16x8*)(Bw + row*256 + ch*8);
  }
  __syncthreads();

  // per-lane bias for cols fr*16..fr*16+15
  float bv[16];
  #pragma unroll
  for (int j = 0; j < 4; ++j)
    *(float4*)&bv[j*4] = *(const float4*)(bias + fr*16 + j*4);

  // one 32-row strip per wave: 448*8 = 3584 = SROW/32
  const int rbase = (blockIdx.x*8 + wid) * 32;

  bf16x8 a[2][8];
  #pragma unroll
  for (int h = 0; h < 2; ++h)
    #pragma unroll
    for (int ks = 0; ks < 8; ++ks)
      a[h][ks] = *(const bf16x8*)(srcbf + (long)(rbase + h*16 + fr)*256 + ks*32 + fq*8);

  f32x4 acc[2][16] = {};
  #pragma unroll
  for (int ks = 0; ks < 8; ++ks) {
    #pragma unroll
    for (int nt = 0; nt < 16; ++nt) {
      const bf16x8 b = *(const bf16x8*)&Bs[(fr*16 + nt)*VLS + (((ks*4 + fq) ^ (fr & 7)))*8];
      acc[0][nt] = MFMA(a[0][ks], b, acc[0][nt]);
      acc[1][nt] = MFMA(a[1][ks], b, acc[1][nt]);
    }
  }

  #pragma unroll
  for (int h = 0; h < 2; ++h) {
    #pragma unroll
    for (int r = 0; r < 4; ++r) {
      const int grow = rbase + h*16 + fq*4 + r;
      const float msc = rowmask[grow] ? 0.0f : 1.0f;
      bf16x8 o0, o1;
      #pragma unroll
      for (int j = 0; j < 8; ++j) {
        o0[j] = f2bf((acc[h][j][r]   + bv[j])   * msc);
        o1[j] = f2bf((acc[h][8+j][r] + bv[8+j]) * msc);
      }
      short* cp = Cb + (long)grow*256 + fr*16;
      *(bf16x8*)cp       = o0;
      *(bf16x8*)(cp + 8) = o1;
    }
  }
}

// ---------------- GEMM 64x64 tile, A[M,K] @ B[N,K]^T + bias (R3-proven) ----------------
// EPI: 0 plain, 1 relu->Cb, 2 qpos, 3 sain-route, 4 two-bias->Cf
template<int EPI>
__global__ __launch_bounds__(256)
void gemm64(const short* __restrict__ A, const short* __restrict__ B,
            const float* __restrict__ bias, const float* __restrict__ bias2,
            float* __restrict__ Cf, short* __restrict__ Cb, short* __restrict__ Cb2,
            int M, int N, int K, int ldc,
            const float* __restrict__ rawq, const float* __restrict__ resid)
{
  __shared__ short As[2][64*64];
  __shared__ short Bs[2][64*64];
  const int tid = threadIdx.x, wid = tid >> 6, lane = tid & 63;
  const int wr = wid >> 1, wc = wid & 1;
  const int fr = lane & 15, fq = lane >> 4;
  const int bm = blockIdx.x, bn = blockIdx.y;
  const int lrow = lane >> 3;
  const int schk = ((lane & 7) ^ lrow) * 8;
  const int nk = K >> 6;

  f32x4 acc[2][2] = {};

  auto stg = [&](int kt, int bsel) {
    const int k0 = kt << 6;
    #pragma unroll
    for (int i = 0; i < 2; ++i) {
      const int rr = wid*16 + i*8 + lrow;
      load_lds16(A + (long)(bm*64 + rr)*K + k0 + schk, &As[bsel][(wid*16 + i*8)*64]);
      load_lds16(B + (long)(bn*64 + rr)*K + k0 + schk, &Bs[bsel][(wid*16 + i*8)*64]);
    }
  };

  stg(0, 0);
  for (int t = 0; t < nk; ++t) {
    const int cur = t & 1;
    if (t + 1 < nk) {
      stg(t + 1, cur ^ 1);
      asm volatile("s_waitcnt vmcnt(4)" ::: "memory");
    } else {
      asm volatile("s_waitcnt vmcnt(0)" ::: "memory");
    }
    __builtin_amdgcn_s_barrier();
    __builtin_amdgcn_sched_barrier(0);
    #pragma unroll
    for (int kk = 0; kk < 64; kk += 32) {
      bf16x8 af[2], bv[2];
      #pragma unroll
      for (int mi = 0; mi < 2; ++mi)
        af[mi] = *(const bf16x8*)&As[cur][(wr*32 + mi*16 + fr)*64 + (((kk>>3)+fq) ^ (fr&7))*8];
      #pragma unroll
      for (int ni = 0; ni < 2; ++ni)
        bv[ni] = *(const bf16x8*)&Bs[cur][(wc*32 + ni*16 + fr)*64 + (((kk>>3)+fq) ^ (fr&7))*8];
      #pragma unroll
      for (int mi = 0; mi < 2; ++mi)
        #pragma unroll
        for (int ni = 0; ni < 2; ++ni)
          acc[mi][ni] = MFMA(af[mi], bv[ni], acc[mi][ni]);
    }
    __builtin_amdgcn_s_barrier();
  }

  #pragma unroll
  for (int mi = 0; mi < 2; ++mi) {
    #pragma unroll
    for (int r = 0; r < 4; ++r) {
      const int grow = bm*64 + wr*32 + mi*16 + fq*4 + r;
      #pragma unroll
      for (int ni = 0; ni < 2; ++ni) {
        const int gcol = bn*64 + wc*32 + ni*16 + fr;
        float v = acc[mi][ni][r];
        if (EPI == 4) v += (gcol < 96) ? bias[gcol] : bias2[gcol-96];
        else v += bias[gcol];
        const long off = (long)grow*ldc + gcol;
        if (EPI == 0) {
          if (Cf) Cf[off] = v;
          if (Cb) Cb[off] = f2bf(v);
        } else if (EPI == 1) {
          Cb[off] = f2bf(fmaxf(v, 0.0f));
        } else if (EPI == 2) {
          const float qp = v * rawq[off];
          Cf[off] = qp;
          Cb[off] = f2bf(resid[off] + qp);
        } else if (EPI == 3) {
          if (grow < MROW) { if (gcol < 512) Cb[(long)grow*512 + gcol] = f2bf(v); }
          else             { if (gcol >= 512) Cb2[(long)(grow-MROW)*256 + gcol-512] = f2bf(v); }
        } else if (EPI == 4) {
          Cf[off] = v;
        }
      }
    }
  }
}

// ---------------- out = tgt (f32 + bf16 copies) ----------------
__global__ __launch_bounds__(256)
void ew0_kernel(const float* __restrict__ tgt, float* __restrict__ out, short* __restrict__ outbf)
{
  const long i = (long)blockIdx.x*256 + threadIdx.x;
  const float4 v = ((const float4*)tgt)[i];
  ((float4*)out)[i] = v;
  ((short4*)outbf)[i] = make_short4(f2bf(v.x), f2bf(v.y), f2bf(v.z), f2bf(v.w));
}

// ---------------- ref / ref_in / sine embedding ----------------
__global__ __launch_bounds__(256)
void init_ref_kernel(const float* __restrict__ seg, const float* __restrict__ dur,
                     const float* __restrict__ valid,
                     short* __restrict__ sinebf, float* __restrict__ refin)
{
  const int m = blockIdx.x;
  const int n = m / LQN;
  const int t = threadIdx.x;
  const float c = seg[(long)m*2 + 0];
  const float w = __expf(seg[(long)m*2 + 1]);
  const float e = (float)(t & ~1) * (1.0f/256.0f);
  const float invdim = __expf(-e * 9.2103403719761836f);
  const float twopi = 6.2831853071795864f;
  const float a0 = c * twopi * invdim;
  const float a1 = w * twopi * invdim;
  const float v0 = (t & 1) ? cosf(a0) : sinf(a0);
  const float v1 = (t & 1) ? cosf(a1) : sinf(a1);
  sinebf[(long)m*512 + t]       = f2bf(v0);
  sinebf[(long)m*512 + 256 + t] = f2bf(v1);
  if (t < 6) {
    const int l = t >> 1, cc = t & 1;
    const float rv = cc ? w : c;
    refin[(long)m*6 + l*2 + cc] = rv / dur[n] * valid[n*NLV + l];
  }
}

// ---------------- MFMA attention ----------------
#define KPAD 320
#define KSTR 40
#define VSTR 328
#define PSTR 328

__global__ __launch_bounds__(256)
void attn_mfma(const short* __restrict__ qk, const short* __restrict__ vv,
               short* __restrict__ outb)
{
  __shared__ short Kl[KPAD*KSTR];
  __shared__ short Vt[DH*VSTR];
  __shared__ short Pl[4][16*PSTR];
  const int b = blockIdx.x;
  const int half = b & 1, h = (b >> 1) & 7, n = b >> 4;
  const int tid = threadIdx.x, wid = tid >> 6, lane = tid & 63;
  const int fr = lane & 15, fq = lane >> 4;

  const short* qkn = qk + (long)n*LQN*512;
  const short* vn  = vv + (long)n*LQN*256;

  for (int t = tid; t < KPAD*4; t += 256) {
    const int r = t >> 2, c = t & 3;
    bf16x8 kv = {}, vw = {};
    if (r < LQN) {
      kv = *(const bf16x8*)(qkn + (long)r*512 + 256 + h*32 + c*8);
      vw = *(const bf16x8*)(vn  + (long)r*256 + h*32 + c*8);
    }
    *(bf16x8*)&Kl[r*KSTR + c*8] = kv;
    #pragma unroll
    for (int j = 0; j < 8; ++j) Vt[(c*8+j)*VSTR + r] = vw[j];
  }
  for (int t = tid; t < 4*16*24; t += 256) {
    const int w = t / (16*24), rr = (t / 24) & 15, cc = t % 24;
    Pl[w][rr*PSTR + 304 + cc] = 0;
  }
  __syncthreads();

  const int tlo = half ? 10 : 0, thi = half ? 19 : 10;
  const float scl2 = 0.17677669529663687f * 1.4426950408889634f;

  for (int qt = tlo + wid; qt < thi; qt += 4) {
    const int q0 = qt * 16;
    const int qrow = min(q0 + fr, LQN-1);
    const bf16x8 qf = *(const bf16x8*)(qkn + (long)qrow*512 + h*32 + fq*8);
    f32x4 s[19];
    #pragma unroll
    for (int t = 0; t < 19; ++t) {
      const bf16x8 kf = *(const bf16x8*)&Kl[(t*16+fr)*KSTR + fq*8];
      s[t] = MFMA(qf, kf, ((f32x4){0.f,0.f,0.f,0.f}));
    }
    float mx[4] = {-3e38f,-3e38f,-3e38f,-3e38f};
    #pragma unroll
    for (int t = 0; t < 19; ++t) {
      const bool valid = (t < 18) || (fr < 12);
      #pragma unroll
      for (int r = 0; r < 4; ++r) if (valid) mx[r] = fmaxf(mx[r], s[t][r]);
    }
    #pragma unroll
    for (int r = 0; r < 4; ++r) {
      #pragma unroll
      for (int o = 1; o < 16; o <<= 1) mx[r] = fmaxf(mx[r], __shfl_xor(mx[r], o));
      mx[r] *= scl2;
    }
    float l[4] = {0.f,0.f,0.f,0.f};
    #pragma unroll
    for (int t = 0; t < 19; ++t) {
      const bool valid = (t < 18) || (fr < 12);
      #pragma unroll
      for (int r = 0; r < 4; ++r) {
        const float p = valid ? exp2f(s[t][r]*scl2 - mx[r]) : 0.0f;
        l[r] += p;
        Pl[wid][(fq*4+r)*PSTR + t*16 + fr] = f2bf(p);
      }
    }
    #pragma unroll
    for (int r = 0; r < 4; ++r) {
      #pragma unroll
      for (int o = 1; o < 16; o <<= 1) l[r] += __shfl_xor(l[r], o);
    }
    f32x4 o0 = {}, o1 = {};
    #pragma unroll
    for (int ck = 0; ck < 10; ++ck) {
      const bf16x8 pf = *(const bf16x8*)&Pl[wid][fr*PSTR + ck*32 + fq*8];
      const bf16x8 v0 = *(const bf16x8*)&Vt[fr*VSTR + ck*32 + fq*8];
      const bf16x8 v1 = *(const bf16x8*)&Vt[(16+fr)*VSTR + ck*32 + fq*8];
      o0 = MFMA(pf, v0, o0);
      o1 = MFMA(pf, v1, o1);
    }
    #pragma unroll
    for (int r = 0; r < 4; ++r) {
      const int qq = q0 + fq*4 + r;
      if (qq < LQN) {
        const float inv = 1.0f / l[r];
        outb[((long)(n*LQN+qq))*256 + h*32 + fr]      = f2bf(o0[r]*inv);
        outb[((long)(n*LQN+qq))*256 + h*32 + 16 + fr] = f2bf(o1[r]*inv);
      }
    }
  }
}

// ---------------- residual + LayerNorm (+ optional caq = y+qpos) ----------------
__global__ __launch_bounds__(256)
void ln_kernel(const float* __restrict__ resid, const float* __restrict__ delta,
               const float* __restrict__ g, const float* __restrict__ b,
               float* __restrict__ of, short* __restrict__ ob,
               const float* __restrict__ qpos, short* __restrict__ caqb)
{
  const int m = blockIdx.x, c = threadIdx.x;
  const long idx = (long)m*DM + c;
  const float x = resid[idx] + delta[idx];
  float s = x, s2 = x*x;
  #pragma unroll
  for (int o = 1; o < 64; o <<= 1) { s += __shfl_xor(s, o); s2 += __shfl_xor(s2, o); }
  __shared__ float rs[4], rs2[4];
  const int w = c >> 6;
  if ((c & 63) == 0) { rs[w] = s; rs2[w] = s2; }
  __syncthreads();
  s  = rs[0]+rs[1]+rs[2]+rs[3];
  s2 = rs2[0]+rs2[1]+rs2[2]+rs2[3];
  const float mean = s * (1.0f/DM);
  const float var  = s2 * (1.0f/DM) - mean*mean;
  const float y = (x - mean) * rsqrtf(var + 1e-5f) * g[c] + b[c];
  of[idx] = y;
  if (ob) ob[idx] = f2bf(y);
  if (qpos) caqb[idx] = f2bf(y + qpos[idx]);
}

// ---------------- sampling: fused prep (softmax+bilinear) + gather-MAC ----------------
__global__ __launch_bounds__(256)
void sample_kernel(const short* __restrict__ val, int ldv,
                   const float* __restrict__ offaw, const float* __restrict__ refin,
                   const int* __restrict__ tlens, const int* __restrict__ lstart,
                   short* __restrict__ cab)
{
  const int m = blockIdx.x;
  const int n = m / LQN;
  const int tid = threadIdx.x;
  __shared__ int2  lI[96];
  __shared__ float2 lW[96];
  if ((tid & 31) == 0) {
    const int h = tid >> 5;
    const float* row = offaw + (long)m*192;
    float aw[12];
    float mx = -1e30f;
    #pragma unroll
    for (int lp = 0; lp < 12; ++lp) { aw[lp] = row[96 + h*12 + lp]; mx = fmaxf(mx, aw[lp]); }
    float sum = 0.0f;
    #pragma unroll
    for (int lp = 0; lp < 12; ++lp) { aw[lp] = __expf(aw[lp]-mx); sum += aw[lp]; }
    const float invs = 1.0f / sum;
    #pragma unroll
    for (int lp = 0; lp < 12; ++lp) {
      const int l = lp >> 2;
      const int tli = tlens[l];
      const float off = row[h*12 + lp];
      const float loc = refin[(long)m*6 + l*2] + off * 0.25f * refin[(long)m*6 + l*2 + 1] * 0.5f;
      const float x = loc * (float)tli - 0.5f;
      const float x0f = floorf(x);
      const float f = x - x0f;
      const int x0 = (int)x0f;
      const int i0 = lstart[l] + min(max(x0,   0), tli-1);
      const int i1 = lstart[l] + min(max(x0+1, 0), tli-1);
      const float wgt = aw[lp]*invs;
      const float w0 = (x0   >= 0 && x0   < tli) ? wgt*(1.0f-f) : 0.0f;
      const float w1 = (x0+1 >= 0 && x0+1 < tli) ? wgt*f        : 0.0f;
      lI[h*12 + lp] = make_int2(i0, i1);
      lW[h*12 + lp] = make_float2(w0, w1);
    }
  }
  __syncthreads();
  const int h = tid >> 5;
  const short* vb = val + (long)n*TT*ldv;
  float acc = 0.0f;
  #pragma unroll
  for (int lp = 0; lp < 12; ++lp) {
    const int e = h*12 + lp;
    const int2 ii = lI[e];
    const float2 ww = lW[e];
    acc += ww.x * bf2f(vb[(long)ii.x*ldv + tid]) + ww.y * bf2f(vb[(long)ii.y*ldv + tid]);
  }
  cab[(long)m*DM + tid] = f2bf(acc);
}

// ---------------- host side ----------------
static inline void g64(hipStream_t st, int epi, const short* A, const short* B,
                       const float* bias, const float* bias2,
                       float* Cf, short* Cb, short* Cb2,
                       int M, int N, int K, int ldc,
                       const float* rawq = nullptr, const float* resid = nullptr)
{
  dim3 g(M/64, N/64), blk(256);
  switch (epi) {
    case 0: gemm64<0><<<g,blk,0,st>>>(A,B,bias,bias2,Cf,Cb,Cb2,M,N,K,ldc,rawq,resid); break;
    case 1: gemm64<1><<<g,blk,0,st>>>(A,B,bias,bias2,Cf,Cb,Cb2,M,N,K,ldc,rawq,resid); break;
    case 2: gemm64<2><<<g,blk,0,st>>>(A,B,bias,bias2,Cf,Cb,Cb2,M,N,K,ldc,rawq,resid); break;
    case 3: gemm64<3><<<g,blk,0,st>>>(A,B,bias,bias2,Cf,Cb,Cb2,M,N,K,ldc,rawq,resid); break;
    default:gemm64<4><<<g,blk,0,st>>>(A,B,bias,bias2,Cf,Cb,Cb2,M,N,K,ldc,rawq,resid); break;
  }
}

extern "C" void kernel_launch(void* const* d_in, const int* in_sizes, int n_in,
                              void* d_out, int out_size, void* d_ws, size_t ws_size,
                              hipStream_t stream)
{
  const float* tgt    = (const float*)d_in[0];
  const float* seg    = (const float*)d_in[1];
  const float* dur    = (const float*)d_in[2];
  const float* src    = (const float*)d_in[3];
  const int*   tlens  = (const int*)d_in[4];
  const int*   lstart = (const int*)d_in[5];
  const float* valid  = (const float*)d_in[6];
  const unsigned char* pmask = (const unsigned char*)d_in[7];
  const float* grid_w0 = (const float*)d_in[8];
  const float* grid_b0 = (const float*)d_in[9];
  const float* grid_w1 = (const float*)d_in[10];
  const float* grid_b1 = (const float*)d_in[11];
  const float* qs_w0 = (const float*)d_in[12];
  const float* qs_b0 = (const float*)d_in[13];
  const float* qs_w1 = (const float*)d_in[14];
  const float* qs_b1 = (const float*)d_in[15];
  const float* sa_in_w  = (const float*)d_in[16];
  const float* sa_in_b  = (const float*)d_in[17];
  const float* sa_out_w = (const float*)d_in[18];
  const float* sa_out_b = (const float*)d_in[19];
  const float* n1_g = (const float*)d_in[20];
  const float* n1_b = (const float*)d_in[21];
  const float* n2_g = (const float*)d_in[22];
  const float* n2_b = (const float*)d_in[23];
  const float* n3_g = (const float*)d_in[24];
  const float* n3_b = (const float*)d_in[25];
  const float* off_w = (const float*)d_in[26];
  const float* off_b = (const float*)d_in[27];
  const float* aw_w  = (const float*)d_in[28];
  const float* aw_b  = (const float*)d_in[29];
  const float* val_w = (const float*)d_in[30];
  const float* val_b = (const float*)d_in[31];
  const float* outp_w = (const float*)d_in[32];
  const float* outp_b = (const float*)d_in[33];
  const float* ffn_w1 = (const float*)d_in[34];
  const float* ffn_b1 = (const float*)d_in[35];
  const float* ffn_w2 = (const float*)d_in[36];
  const float* ffn_b2 = (const float*)d_in[37];

  // bf16 weight region offsets (shorts); src bf16 follows weights
  const long W_G0=0, W_G1=131072, W_QS0=196608, W_QS1=262144, W_SAIN=327680,
             W_SAOUT=1507328, W_OFFAW=1900544, W_VAL=2195456,
             W_OUTP=2588672, W_FFN1=2981888, W_FFN2=4554752, W_SRC=6127616;

  char* ws = (char*)d_ws;
  short* wbf    = (short*)(ws + 0);
  short* srcbf  = wbf + W_SRC;
  short* sinebf = (short*)(ws + 70975488);
  short* ghbf   = (short*)(ws + 75890688);
  float* rawq   = (float*)(ws + 78348288);
  float* out    = (float*)(ws + 83263488);
  short* qcat   = (short*)(ws + 88178688);    // [9600][256]: qbf rows 0..4799, outbf 4800..
  short* qbf    = qcat;
  short* outbf  = qcat + (long)MROW*DM;
  short* t1bf   = (short*)(ws + 93093888);
  float* qpos   = (float*)(ws + 95551488);
  short* qkbf   = (short*)(ws + 100466688);   // [4800][512]
  short* vbf    = (short*)(ws + 105381888);   // [4800][256]
  short* attnbf = (short*)(ws + 107839488);
  float* tmpf   = (float*)(ws + 110297088);
  short* caqb   = (short*)(ws + 115212288);
  float* offaw  = (float*)(ws + 117669888);   // [4800][192]
  short* cabf   = (short*)(ws + 128729088);
  short* ffnhbf = (short*)(ws + 131186688);
  float* refin  = (float*)(ws + 141017088);
  short* valbf  = (short*)(ws + 141132288);   // [114688][256]

  CvtPtrs cp;
  cp.p[0]=grid_w0; cp.p[1]=grid_w1; cp.p[2]=qs_w0; cp.p[3]=qs_w1; cp.p[4]=sa_in_w;
  cp.p[5]=sa_out_w; cp.p[6]=off_w; cp.p[7]=aw_w; cp.p[8]=val_w; cp.p[9]=outp_w;
  cp.p[10]=ffn_w1; cp.p[11]=ffn_w2; cp.p[12]=src;
  cvt_all_kernel<<<dim3(34656), dim3(256), 0, stream>>>(cp, wbf);

  ew0_kernel<<<dim3(1200), dim3(256), 0, stream>>>(tgt, out, outbf);
  init_ref_kernel<<<dim3(MROW), dim3(256), 0, stream>>>(seg, dur, valid, sinebf, refin);

  g64(stream, 1, sinebf, wbf + W_G0, grid_b0, nullptr, nullptr, ghbf, nullptr, MROW, 256, 512, 256);
  g64(stream, 0, ghbf,   wbf + W_G1, grid_b1, nullptr, rawq, nullptr, nullptr, MROW, 256, 256, 256);

  for (int l = 0; l < NLAY; ++l) {
    g64(stream, 1, outbf, wbf + W_QS0, qs_b0, nullptr, nullptr, t1bf, nullptr, MROW, 256, 256, 256);
    g64(stream, 2, t1bf,  wbf + W_QS1, qs_b1, nullptr, qpos, qbf, nullptr, MROW, 256, 256, 256,
        rawq, out);
    g64(stream, 3, qcat, wbf + W_SAIN + (long)l*196608, sa_in_b + l*768, nullptr,
        nullptr, qkbf, vbf, 2*MROW, 768, 256, 0);
    attn_mfma<<<dim3(256), dim3(256), 0, stream>>>(qkbf, vbf, attnbf);
    g64(stream, 0, attnbf, wbf + W_SAOUT + (long)l*65536, sa_out_b + l*256, nullptr,
        tmpf, nullptr, nullptr, MROW, 256, 256, 256);
    ln_kernel<<<dim3(MROW), dim3(256), 0, stream>>>(out, tmpf, n1_g + l*256, n1_b + l*256,
                                                    out, outbf, qpos, caqb);
    g64(stream, 4, caqb, wbf + W_OFFAW + (long)l*49152, off_b + l*96, aw_b + l*96,
        offaw, nullptr, nullptr, MROW, 192, 256, 192);
    val_gemm<<<dim3(448), dim3(512), 0, stream>>>(
        srcbf, wbf + W_VAL + (long)l*65536, val_b + l*256, valbf, pmask);
    sample_kernel<<<dim3(MROW), dim3(256), 0, stream>>>(
        valbf, 256, offaw, refin, tlens, lstart, cabf);
    g64(stream, 0, cabf, wbf + W_OUTP + (long)l*65536, outp_b + l*256, nullptr,
        tmpf, nullptr, nullptr, MROW, 256, 256, 256);
    ln_kernel<<<dim3(MROW), dim3(256), 0, stream>>>(out, tmpf, n2_g + l*256, n2_b + l*256,
                                                    out, outbf, nullptr, nullptr);
    g64(stream, 1, outbf, wbf + W_FFN1 + (long)l*262144, ffn_b1 + l*1024, nullptr,
        nullptr, ffnhbf, nullptr, MROW, 1024, 256, 1024);
    g64(stream, 0, ffnhbf, wbf + W_FFN2 + (long)l*262144, ffn_b2 + l*256, nullptr,
        tmpf, nullptr, nullptr, MROW, 256, 1024, 256);
    float* of = (l == NLAY-1) ? (float*)d_out : out;
    ln_kernel<<<dim3(MROW), dim3(256), 0, stream>>>(out, tmpf, n3_g + l*256, n3_b + l*256,
                                                    of, outbf, nullptr, nullptr);
  }
}